// Round 6
// baseline (300.683 us; speedup 1.0000x reference)
//
#include <hip/hip_runtime.h>
#include <hip/hip_bf16.h>

// Problem constants
#define Bc 2
#define Tc 2048
#define Cc 2048
#define Hc 16
#define Dc 128
#define BTc 4096
#define NQ 6144            // 3*Cc
#define EPSc 1e-5f
#define QSCALE 0.08838834764831845f   // 1/sqrt(128)

typedef __attribute__((ext_vector_type(8))) short bf16x8;
typedef __attribute__((ext_vector_type(4))) short bf16x4;
typedef __attribute__((ext_vector_type(4))) float f32x4;

__device__ __forceinline__ f32x4 mfma16(bf16x8 a, bf16x8 b, f32x4 c) {
  return __builtin_amdgcn_mfma_f32_16x16x32_bf16(a, b, c, 0, 0, 0);
}

__device__ __forceinline__ void gload16(const void* g, void* l) {
  __builtin_amdgcn_global_load_lds(
      (const __attribute__((address_space(1))) void*)g,
      (__attribute__((address_space(3))) void*)l, 16, 0, 0);
}

// ---------------- fp32 -> bf16 convert (x) ----------------
__global__ __launch_bounds__(256) void k_xconv(const float* __restrict__ x,
                                               __hip_bfloat16* __restrict__ xb) {
  size_t i = ((size_t)blockIdx.x * 256 + threadIdx.x) * 4;
  float4 v = *(const float4*)(x + i);
  union { __hip_bfloat16 h[4]; bf16x4 v4; } u;
  u.h[0] = __float2bfloat16(v.x); u.h[1] = __float2bfloat16(v.y);
  u.h[2] = __float2bfloat16(v.z); u.h[3] = __float2bfloat16(v.w);
  *(bf16x4*)(xb + i) = u.v4;
}

// ------- weight transpose+convert: W (K x N) fp32 -> Wt (N x K) bf16 -------
__global__ __launch_bounds__(256) void k_wconv(const float* __restrict__ Wq,
    const float* __restrict__ Wk, const float* __restrict__ Wv,
    const float* __restrict__ Wp, __hip_bfloat16* __restrict__ Wqkv_t,
    __hip_bfloat16* __restrict__ Wproj_t) {
  __shared__ float tile[64][65];
  int z = blockIdx.z;
  const float* src = (z == 0) ? Wq : (z == 1) ? Wk : (z == 2) ? Wv : Wp;
  __hip_bfloat16* dst = (z < 3) ? (Wqkv_t + (size_t)z * Cc * Cc) : Wproj_t;
  int k0 = blockIdx.x * 64, n0 = blockIdx.y * 64;
  int c = threadIdx.x & 63, rb = threadIdx.x >> 6;
  for (int i = 0; i < 16; i++) {
    int r = rb * 16 + i;
    tile[r][c] = src[(size_t)(k0 + r) * Cc + n0 + c];
  }
  __syncthreads();
  for (int i = 0; i < 16; i++) {
    int r = rb * 16 + i;
    dst[(size_t)(n0 + r) * Cc + k0 + c] = __float2bfloat16(tile[c][r]);
  }
}

// ============ 256x256 8-phase GEMM v3 (kk-split quadrants) =================
// C[m][n] = sum_k A[m][k]*Bt[n][k].  8 waves (2Mx4N), BK=64/K-tile.
// LDS 8 slots x 16KB: buf0 A-kk0@0 A-kk1@16K B-kk0@32K B-kk1@48K; buf1 +64K.
// Slot = 256 rows x 32 K-cols, row r at (r&127)*64 + (r>>7)*8192, 16B-chunk
// XOR swizzle chunk^=((row>>1)&3) (staging pre-swizzles the GLOBAL column).
// Phase = (M-half, K-half) quadrant: 16 MFMA (4m x 4n x 1kk); reads/phase
// 8 (A4+B4 on kk change) or 4 (A4, B reused) per m201's "4 or 8" constraint.
// Stage 1 slot (2 gloads)/phase; vmcnt(2) at ph4/ph8 only.  All stage->slot
// overwrite hazards and landing deadlines verified (see round-6 derivation).
__device__ __forceinline__ void rdA4(bf16x8 (&d)[4], const char* p) {
#pragma unroll
  for (int m = 0; m < 4; m++) d[m] = *(const bf16x8*)(p + m * 1024);
}
__device__ __forceinline__ void rdB4(bf16x8 (&d)[4], const char* p) {
#pragma unroll
  for (int n = 0; n < 4; n++) d[n] = *(const bf16x8*)(p + n * 1024);
}
template <int MH>
__device__ __forceinline__ void mmS(f32x4 (&acc)[8][4], const bf16x8 (&A_)[4],
                                    const bf16x8 (&B_)[4]) {
  __builtin_amdgcn_s_setprio(1);
#pragma unroll
  for (int m = 0; m < 4; m++)
#pragma unroll
    for (int n = 0; n < 4; n++)
      acc[MH * 4 + m][n] = mfma16(A_[m], B_[n], acc[MH * 4 + m][n]);
  __builtin_amdgcn_s_setprio(0);
}

template <typename OutT>
__global__ __launch_bounds__(512, 2) void k_gemm8(const __hip_bfloat16* __restrict__ A,
    const __hip_bfloat16* __restrict__ Bt, OutT* __restrict__ Co,
    int M, int N, int K) {
  __shared__ __align__(16) char lds[131072];
  const int nbx = M >> 8;
  const int nwg = nbx * (N >> 8);              // divisible by 8 for our shapes
  const int wg = blockIdx.x;
  const int swz = (wg & 7) * (nwg >> 3) + (wg >> 3);
  const int bx = swz % nbx, by = swz / nbx;
  const int tid = threadIdx.x, lane = tid & 63, wid = tid >> 6;
  const int wr = wid >> 2, wc = wid & 3;
  const int lr = lane & 15, lg = lane >> 4;
  const int roff = lr * 64 + (lg ^ ((lr >> 1) & 3)) * 16;
  // staging: thread covers rows srow, srow+128 at swizzled source column
  const int srow = wid * 16 + (lane >> 2);
  const int scol = (((lane & 3) ^ ((srow >> 1) & 3)) << 3);
  const __hip_bfloat16* Ag = A + (size_t)(bx * 256 + srow) * K + scol;
  const __hip_bfloat16* Bg = Bt + (size_t)(by * 256 + srow) * K + scol;
  char* ldsw = lds + wid * 1024;
  const size_t rstep = (size_t)128 * K;
  // read bases: A(buf,kk,mh) = bufA + kk*16384 + wr*8192 + mh*4096 (+m*1024)
  //             B(buf,kk)    = bufB + kk*16384 + wc*4096          (+n*1024)
  const char* A00 = lds + 0     + wr * 8192 + roff;
  const char* B0  = lds + 32768 + wc * 4096 + roff;
  const char* A10 = lds + 65536 + wr * 8192 + roff;
  const char* B1  = lds + 98304 + wc * 4096 + roff;

#define STG(slotoff, gp, t, ks) { const __hip_bfloat16* g_ = (gp) + (t) * 64 + (ks) * 32; \
    gload16(g_, ldsw + (slotoff)); gload16(g_ + rstep, ldsw + (slotoff) + 8192); }
#define BARRIER __builtin_amdgcn_s_barrier()
#define VW2 asm volatile("s_waitcnt vmcnt(2)" ::: "memory")
#define LGKM0 asm volatile("s_waitcnt lgkmcnt(0)" ::: "memory")
#define SB0 __builtin_amdgcn_sched_barrier(0)

  f32x4 acc[8][4];
#pragma unroll
  for (int m = 0; m < 8; m++)
#pragma unroll
    for (int n = 0; n < 4; n++) acc[m][n] = f32x4{0.f, 0.f, 0.f, 0.f};
  bf16x8 rAp[4], rAq[4], rBp[4], rBq[4];

  const int NT = K >> 6, NIT = K >> 7;   // NT even
  // prologue: tile0 all 4 slots + A(1)kk0
  STG(0, Ag, 0, 0); STG(16384, Ag, 0, 1);
  STG(32768, Bg, 0, 0); STG(49152, Bg, 0, 1);
  STG(65536, Ag, 1, 0);
  VW2;            // tile0 landed; A(1)kk0 may be outstanding
  BARRIER;

  for (int it = 0; it < NIT; ++it) {
    const int tb = 2 * it + 1;
    const int tn2 = (2 * it + 2 < NT) ? 2 * it + 2 : NT - 1;  // clamped last iter
    const int tn3 = (2 * it + 3 < NT) ? 2 * it + 3 : NT - 1;
    // ---- tile 2i (buf0): phases (mh0,kk0)(mh1,kk0)(mh0,kk1)(mh1,kk1) ----
    // ph1
    rdA4(rAp, A00);
    rdB4(rBp, B0);
    STG(81920, Ag, tb, 1);          // buf1 A-kk1 (read ph7/ph8)
    BARRIER; LGKM0; SB0;
    mmS<0>(acc, rAp, rBp);
    BARRIER;
    // ph2
    rdA4(rAq, A00 + 4096);
    STG(114688, Bg, tb, 1);         // buf1 B-kk1 (read ph7)
    BARRIER; LGKM0; SB0;
    mmS<1>(acc, rAq, rBp);
    BARRIER;
    // ph3
    rdA4(rAp, A00 + 16384);
    rdB4(rBq, B0 + 16384);
    STG(98304, Bg, tb, 0);          // buf1 B-kk0 (read ph5)
    BARRIER; LGKM0; SB0;
    mmS<0>(acc, rAp, rBq);
    BARRIER;
    // ph4
    rdA4(rAq, A00 + 16384 + 4096);
    STG(0, Ag, tn2, 0);             // buf0 A-kk0 (read next ph1/ph2)
    BARRIER; LGKM0; SB0;
    mmS<1>(acc, rAq, rBq);
    VW2;
    BARRIER;
    // ---- tile 2i+1 (buf1) ----
    // ph5
    rdA4(rAp, A10);
    rdB4(rBp, B1);
    STG(16384, Ag, tn2, 1);         // buf0 A-kk1 (read next ph3/ph4)
    BARRIER; LGKM0; SB0;
    mmS<0>(acc, rAp, rBp);
    BARRIER;
    // ph6
    rdA4(rAq, A10 + 4096);
    STG(32768, Bg, tn2, 0);         // buf0 B-kk0 (read next ph1)
    BARRIER; LGKM0; SB0;
    mmS<1>(acc, rAq, rBp);
    BARRIER;
    // ph7
    rdA4(rAp, A10 + 16384);
    rdB4(rBq, B1 + 16384);
    STG(49152, Bg, tn2, 1);         // buf0 B-kk1 (read next ph3)
    BARRIER; LGKM0; SB0;
    mmS<0>(acc, rAp, rBq);
    BARRIER;
    // ph8
    rdA4(rAq, A10 + 16384 + 4096);
    STG(65536, Ag, tn3, 0);         // buf1 A-kk0 (read next ph5/ph6)
    BARRIER; LGKM0; SB0;
    mmS<1>(acc, rAq, rBq);
    VW2;
    BARRIER;
  }
#undef STG

  const int row0 = bx * 256 + wr * 128 + lg * 4;
  const int col0 = by * 256 + wc * 64 + lr;
#pragma unroll
  for (int m = 0; m < 8; m++)
#pragma unroll
    for (int n = 0; n < 4; n++) {
      size_t base = (size_t)(row0 + m * 16) * N + col0 + n * 16;
#pragma unroll
      for (int r = 0; r < 4; r++) {
        float v = acc[m][n][r];
        if constexpr (sizeof(OutT) == 2)
          Co[base + (size_t)r * N] = __float2bfloat16(v);
        else
          Co[base + (size_t)r * N] = v;
      }
    }
}

// ---------------- bf16 GEMM, m97 128x128 structure (for grid-starved proj) -
template <typename OutT>
__global__ __launch_bounds__(256) void k_gemm(const __hip_bfloat16* __restrict__ A,
    const __hip_bfloat16* __restrict__ Bt, OutT* __restrict__ Co,
    int M, int N, int K) {
  __shared__ __align__(16) __hip_bfloat16 As[128][32];
  __shared__ __align__(16) __hip_bfloat16 Bs[128][32];
  const int m0 = blockIdx.x * 128, n0 = blockIdx.y * 128;
  const int w = threadIdx.x >> 6, lane = threadIdx.x & 63;
  const int wr = w >> 1, wc = w & 1;
  const int lr = lane & 15, lg = lane >> 4;
  const int srow = lane >> 2, scolE = (lane & 3) * 8;
  f32x4 zero = {0.f, 0.f, 0.f, 0.f};
  f32x4 acc[4][4];
  for (int m = 0; m < 4; m++)
    for (int n = 0; n < 4; n++) acc[m][n] = zero;
  for (int k0 = 0; k0 < K; k0 += 32) {
    for (int q = 0; q < 2; q++) {
      int row = w * 32 + q * 16 + srow;
      gload16(A  + (size_t)(m0 + row) * K + k0 + scolE, &As[w * 32 + q * 16][0]);
      gload16(Bt + (size_t)(n0 + row) * K + k0 + scolE, &Bs[w * 32 + q * 16][0]);
    }
    __syncthreads();
    bf16x8 af[4], bfm[4];
    for (int m = 0; m < 4; m++) af[m]  = *(const bf16x8*)&As[wr * 64 + m * 16 + lr][lg * 8];
    for (int n = 0; n < 4; n++) bfm[n] = *(const bf16x8*)&Bs[wc * 64 + n * 16 + lr][lg * 8];
    for (int m = 0; m < 4; m++)
      for (int n = 0; n < 4; n++)
        acc[m][n] = mfma16(af[m], bfm[n], acc[m][n]);
    __syncthreads();
  }
  for (int m = 0; m < 4; m++)
    for (int n = 0; n < 4; n++) {
      int row = m0 + wr * 64 + m * 16 + lg * 4;
      int col = n0 + wc * 64 + n * 16 + lr;
      for (int r = 0; r < 4; r++) {
        float v = acc[m][n][r];
        if constexpr (sizeof(OutT) == 2)
          Co[(size_t)(row + r) * N + col] = __float2bfloat16(v);
        else
          Co[(size_t)(row + r) * N + col] = v;
      }
    }
}

// ---------------- in-place QK RMSNorm over head dim (D=128) ----------------
__global__ __launch_bounds__(256) void k_qkrms(__hip_bfloat16* __restrict__ QKV,
    const float* __restrict__ qw, const float* __restrict__ kw) {
  int bt = blockIdx.x;
  int w = threadIdx.x >> 6, lane = threadIdx.x & 63;
  int hv = blockIdx.y * 4 + w;
  const float* wt; int col; float extra;
  if (hv < 16) { wt = qw; col = hv * Dc;             extra = QSCALE; }
  else         { wt = kw; col = Cc + (hv - 16) * Dc; extra = 1.0f;   }
  __hip_bfloat16* p = QKV + (size_t)bt * NQ + col + lane * 2;
  float x0 = __bfloat162float(p[0]);
  float x1 = __bfloat162float(p[1]);
  float ss = x0 * x0 + x1 * x1;
  for (int m = 1; m < 64; m <<= 1) ss += __shfl_xor(ss, m);
  float sc = rsqrtf(ss * (1.0f / Dc) + EPSc) * extra;
  p[0] = __float2bfloat16(x0 * sc * wt[lane * 2]);
  p[1] = __float2bfloat16(x1 * sc * wt[lane * 2 + 1]);
}

// ---------------- V transpose: (b,t,h,d) cols of QKV -> Vt (b,h,d,t) -------
__global__ __launch_bounds__(256) void k_vtrans(const __hip_bfloat16* __restrict__ QKV,
                                                __hip_bfloat16* __restrict__ Vt) {
  __shared__ __hip_bfloat16 tile[64][65];
  int bh = blockIdx.z, t0 = blockIdx.x * 64, d0 = blockIdx.y * 64;
  int b = bh >> 4, h = bh & 15;
  int c = threadIdx.x & 63, rb = threadIdx.x >> 6;
  for (int i = 0; i < 16; i++) {
    int r = rb * 16 + i;
    tile[r][c] = QKV[(size_t)(b * Tc + t0 + r) * NQ + 2 * Cc + h * Dc + d0 + c];
  }
  __syncthreads();
  for (int i = 0; i < 16; i++) {
    int r = rb * 16 + i;
    Vt[((size_t)bh * Dc + d0 + r) * Tc + t0 + c] = tile[c][r];
  }
}

// ---------------- flash attention v2: LDS-staged K/V, dbuf, paired tiles ---
// grid (bh=32, pp=16); 4 waves; block handles q-tiles {31-pp, pp} (64 rows each)
__global__ __launch_bounds__(256, 2) void k_attn(const __hip_bfloat16* __restrict__ QKV,
    const __hip_bfloat16* __restrict__ Vt, const float* __restrict__ subw,
    __hip_bfloat16* __restrict__ Y) {
  __shared__ __align__(16) __hip_bfloat16 Ks[2][64][128];   // 32 KB
  __shared__ __align__(16) __hip_bfloat16 Vs[2][128][64];   // 32 KB
  __shared__ __align__(16) __hip_bfloat16 Plds[4][16][72];  // 9 KB (padded stride 144B)
  const int bh = blockIdx.x, pp = blockIdx.y;
  const int b = bh >> 4, h = bh & 15;
  const int w = threadIdx.x >> 6, lane = threadIdx.x & 63;
  const int lr = lane & 15, lg = lane >> 4;
  const float slope = exp2f(-0.5f * (float)(h + 1));
  const __hip_bfloat16* Kbase = QKV + (size_t)b * Tc * NQ + Cc + h * Dc;
  const __hip_bfloat16* Vbase = Vt + (size_t)bh * Dc * Tc;
  const int krow = (lane >> 4);
  const int kcolb = ((lane & 15) << 4);
  const int vrow = (lane >> 3);
  const int vcolb = ((lane & 7) << 4);
  f32x4 zero = {0.f, 0.f, 0.f, 0.f};

  int buf = 0;
  for (int ti = 0; ti < 2; ti++) {
    const int qt = (ti == 0) ? (31 - pp) : pp;
    const int q0 = qt * 64 + w * 16;
    const int nchunk = qt + 1;
    bf16x8 aq[4];
    {
      const __hip_bfloat16* qb = QKV + (size_t)(b * Tc + q0 + lr) * NQ + h * Dc + lg * 8;
      for (int c = 0; c < 4; c++) aq[c] = *(const bf16x8*)(qb + c * 32);
    }
    f32x4 acc[8];
    for (int d = 0; d < 8; d++) acc[d] = zero;
    float mrow[4] = {-1e30f, -1e30f, -1e30f, -1e30f};
    float lrow[4] = {0.f, 0.f, 0.f, 0.f};

#define STAGE(bb, t)                                                              \
    {                                                                             \
      const int s0_ = (t) * 64;                                                   \
      for (int j = 0; j < 4; j++) {                                               \
        int row = w * 16 + j * 4 + krow;                                          \
        int cb = kcolb ^ ((row & 7) << 4);                                        \
        gload16(Kbase + (size_t)(s0_ + row) * NQ + (cb >> 1),                     \
                &Ks[bb][w * 16 + j * 4][0]);                                      \
      }                                                                           \
      for (int j = 0; j < 4; j++) {                                               \
        int row = w * 32 + j * 8 + vrow;                                          \
        int cb = vcolb ^ ((row & 7) << 4);                                        \
        gload16(Vbase + (size_t)row * Tc + s0_ + (cb >> 1),                       \
                &Vs[bb][w * 32 + j * 8][0]);                                      \
      }                                                                           \
    }

    STAGE(buf, 0);
    __syncthreads();
    for (int t = 0; t < nchunk; t++) {
      if (t + 1 < nchunk) STAGE(buf ^ 1, t + 1);
      const int s0 = t * 64;
      f32x4 s[4];
      for (int ss = 0; ss < 4; ss++) s[ss] = zero;
      __builtin_amdgcn_s_setprio(1);
      for (int c = 0; c < 4; c++)
        for (int ss = 0; ss < 4; ss++) {
          int kr = ss * 16 + lr;
          const bf16x8 kf = *(const bf16x8*)
              &Ks[buf][kr][((c * 64 + lg * 16) ^ ((kr & 7) << 4)) >> 1];
          s[ss] = mfma16(aq[c], kf, s[ss]);
        }
      __builtin_amdgcn_s_setprio(0);
      float ps[4][4], mt[4];
      for (int r = 0; r < 4; r++) mt[r] = -1e30f;
      for (int ss = 0; ss < 4; ss++) {
        int jj = s0 + ss * 16 + lr;
        for (int r = 0; r < 4; r++) {
          int i = q0 + lg * 4 + r;
          float pv = (jj <= i) ? s[ss][r] - slope * (float)(i - jj) : -1e30f;
          ps[ss][r] = pv;
          mt[r] = fmaxf(mt[r], pv);
        }
      }
      for (int m = 1; m < 16; m <<= 1)
        for (int r = 0; r < 4; r++) mt[r] = fmaxf(mt[r], __shfl_xor(mt[r], m));
      float corr[4], rs[4];
      for (int r = 0; r < 4; r++) {
        float mn = fmaxf(mrow[r], mt[r]);
        corr[r] = __expf(mrow[r] - mn);
        mrow[r] = mn;
        rs[r] = 0.f;
      }
      for (int ss = 0; ss < 4; ss++)
        for (int r = 0; r < 4; r++) {
          float e = __expf(ps[ss][r] - mrow[r]);
          ps[ss][r] = e;
          rs[r] += e;
        }
      for (int m = 1; m < 16; m <<= 1)
        for (int r = 0; r < 4; r++) rs[r] += __shfl_xor(rs[r], m);
      for (int r = 0; r < 4; r++) lrow[r] = lrow[r] * corr[r] + rs[r];
      for (int d = 0; d < 8; d++)
        for (int r = 0; r < 4; r++) acc[d][r] *= corr[r];
      for (int ss = 0; ss < 4; ss++)
        for (int r = 0; r < 4; r++)
          Plds[w][lg * 4 + r][ss * 16 + lr] = __float2bfloat16(ps[ss][r]);
      bf16x8 pa0 = *(const bf16x8*)&Plds[w][lr][lg * 8];
      bf16x8 pa1 = *(const bf16x8*)&Plds[w][lr][32 + lg * 8];
      __builtin_amdgcn_s_setprio(1);
      for (int d = 0; d < 8; d++) {
        int vr = d * 16 + lr;
        const bf16x8 b0 = *(const bf16x8*)
            &Vs[buf][vr][((lg * 16) ^ ((vr & 7) << 4)) >> 1];
        const bf16x8 b1 = *(const bf16x8*)
            &Vs[buf][vr][((64 + lg * 16) ^ ((vr & 7) << 4)) >> 1];
        acc[d] = mfma16(pa0, b0, acc[d]);
        acc[d] = mfma16(pa1, b1, acc[d]);
      }
      __builtin_amdgcn_s_setprio(0);
      __syncthreads();
      buf ^= 1;
    }
#undef STAGE
    float ssum[4] = {0.f, 0.f, 0.f, 0.f};
    for (int r = 0; r < 4; r++) {
      float rl = 1.0f / lrow[r];
      for (int d = 0; d < 8; d++) {
        float o = acc[d][r] * rl;
        acc[d][r] = o;
        ssum[r] += o * o;
      }
    }
    for (int m = 1; m < 16; m <<= 1)
      for (int r = 0; r < 4; r++) ssum[r] += __shfl_xor(ssum[r], m);
    float ms[4];
    for (int r = 0; r < 4; r++) ms[r] = rsqrtf(ssum[r] * (1.0f / Dc) + EPSc);
    for (int d = 0; d < 8; d++) {
      float wv = subw[d * 16 + lr];
      for (int r = 0; r < 4; r++) {
        float y = acc[d][r] * ms[r] * wv;
        Y[(size_t)(b * Tc + q0 + lg * 4 + r) * Cc + h * Dc + d * 16 + lr] =
            __float2bfloat16(y);
      }
    }
  }
}

extern "C" void kernel_launch(void* const* d_in, const int* in_sizes, int n_in,
                              void* d_out, int out_size, void* d_ws, size_t ws_size,
                              hipStream_t stream) {
  const float* x  = (const float*)d_in[0];
  const float* Wq = (const float*)d_in[1];
  const float* Wk = (const float*)d_in[2];
  const float* Wv = (const float*)d_in[3];
  const float* Wp = (const float*)d_in[4];
  const float* qw = (const float*)d_in[5];
  const float* kw = (const float*)d_in[6];
  const float* sw = (const float*)d_in[7];
  float* out = (float*)d_out;

  char* ws = (char*)d_ws;
  __hip_bfloat16* Xb    = (__hip_bfloat16*)(ws + 0);          // 16 MiB (4096x2048)
  __hip_bfloat16* Wqkv  = (__hip_bfloat16*)(ws + 16777216);   // 24 MiB (6144x2048, N-major)
  __hip_bfloat16* Wproj = (__hip_bfloat16*)(ws + 41943040);   //  8 MiB (2048x2048, N-major)
  __hip_bfloat16* QKV   = (__hip_bfloat16*)(ws + 50331648);   // 48 MiB (4096x6144)
  __hip_bfloat16* Vt    = (__hip_bfloat16*)(ws + 100663296);  // 16 MiB (b,h,d,t)
  __hip_bfloat16* Yb    = (__hip_bfloat16*)(ws + 117440512);  // 16 MiB (4096x2048)

  k_xconv<<<dim3((BTc * Cc) / 1024), 256, 0, stream>>>(x, Xb);
  k_wconv<<<dim3(32, 32, 4), 256, 0, stream>>>(Wq, Wk, Wv, Wp, Wqkv, Wproj);
  k_gemm8<__hip_bfloat16><<<dim3((BTc / 256) * (NQ / 256)), 512, 0, stream>>>(
      Xb, Wqkv, QKV, BTc, NQ, Cc);
  k_qkrms<<<dim3(BTc, 8), 256, 0, stream>>>(QKV, qw, kw);
  k_vtrans<<<dim3(Tc / 64, Dc / 64, Bc * Hc), 256, 0, stream>>>(QKV, Vt);
  k_attn<<<dim3(Bc * Hc, 16), 256, 0, stream>>>(QKV, Vt, sw, Yb);
  // proj: 128x128 tiles -> 512 wgs (fills all 256 CUs; 256 tile was 128 wgs)
  k_gemm<float><<<dim3(BTc / 128, Cc / 128), 256, 0, stream>>>(
      Yb, Wproj, out, BTc, Cc, Cc);
}

// Round 7
// 295.150 us; speedup vs baseline: 1.0187x; 1.0187x over previous
//
#include <hip/hip_runtime.h>
#include <hip/hip_bf16.h>

// Problem constants
#define Bc 2
#define Tc 2048
#define Cc 2048
#define Hc 16
#define Dc 128
#define BTc 4096
#define NQ 6144            // 3*Cc
#define EPSc 1e-5f
#define QSCALE 0.08838834764831845f   // 1/sqrt(128)

typedef __attribute__((ext_vector_type(8))) short bf16x8;
typedef __attribute__((ext_vector_type(4))) short bf16x4;
typedef __attribute__((ext_vector_type(4))) float f32x4;

__device__ __forceinline__ f32x4 mfma16(bf16x8 a, bf16x8 b, f32x4 c) {
  return __builtin_amdgcn_mfma_f32_16x16x32_bf16(a, b, c, 0, 0, 0);
}

__device__ __forceinline__ void gload16(const void* g, void* l) {
  __builtin_amdgcn_global_load_lds(
      (const __attribute__((address_space(1))) void*)g,
      (__attribute__((address_space(3))) void*)l, 16, 0, 0);
}

// ---------------- fp32 -> bf16 convert (x) ----------------
__global__ __launch_bounds__(256) void k_xconv(const float* __restrict__ x,
                                               __hip_bfloat16* __restrict__ xb) {
  size_t i = ((size_t)blockIdx.x * 256 + threadIdx.x) * 4;
  float4 v = *(const float4*)(x + i);
  union { __hip_bfloat16 h[4]; bf16x4 v4; } u;
  u.h[0] = __float2bfloat16(v.x); u.h[1] = __float2bfloat16(v.y);
  u.h[2] = __float2bfloat16(v.z); u.h[3] = __float2bfloat16(v.w);
  *(bf16x4*)(xb + i) = u.v4;
}

// ------- weight transpose+convert: W (K x N) fp32 -> Wt (N x K) bf16 -------
__global__ __launch_bounds__(256) void k_wconv(const float* __restrict__ Wq,
    const float* __restrict__ Wk, const float* __restrict__ Wv,
    const float* __restrict__ Wp, __hip_bfloat16* __restrict__ Wqkv_t,
    __hip_bfloat16* __restrict__ Wproj_t) {
  __shared__ float tile[64][65];
  int z = blockIdx.z;
  const float* src = (z == 0) ? Wq : (z == 1) ? Wk : (z == 2) ? Wv : Wp;
  __hip_bfloat16* dst = (z < 3) ? (Wqkv_t + (size_t)z * Cc * Cc) : Wproj_t;
  int k0 = blockIdx.x * 64, n0 = blockIdx.y * 64;
  int c = threadIdx.x & 63, rb = threadIdx.x >> 6;
  for (int i = 0; i < 16; i++) {
    int r = rb * 16 + i;
    tile[r][c] = src[(size_t)(k0 + r) * Cc + n0 + c];
  }
  __syncthreads();
  for (int i = 0; i < 16; i++) {
    int r = rb * 16 + i;
    dst[(size_t)(n0 + r) * Cc + k0 + c] = __float2bfloat16(tile[c][r]);
  }
}

// ============ 128x256-tile 8-phase GEMM (ring-3), B pre-transposed =========
// C[m][n] = sum_k A[m][k]*Bt[n][k].  8 waves (2Mx4N), wave tile 64x64,
// BK=64/K-tile, K=2048 fixed (NT=32).  Per phase (2 phases/K-tile):
// 8 ds_read_b128 + 3 global_load_lds + 16 MFMA — the m201 canonical shape.
// LDS ring of 3 bufs x 48KB: A-kk0@0 (8KB), A-kk1@8K, B-kk0@16K (16KB),
// B-kk1@32K.  Rows of 64B (32 K-cols), 16B-chunk XOR swizzle
// chunk ^= ((row>>1)&3); staging pre-swizzles the GLOBAL column (dest
// linear, m173).  Tile t reads buf t%3, stages tile t+2 into buf (t+2)%3
// (never the buf being read; that buf's reads closed >=1 barrier ago).
// vmcnt(6) per tile => exactly tile-(t+2)'s 6 gloads stay in flight;
// tile-(t+1)'s are landed at its first read.  Tail: tile30 VW0, tile31 none.
__device__ __forceinline__ void rdA4(bf16x8 (&d)[4], const char* p) {
#pragma unroll
  for (int m = 0; m < 4; m++) d[m] = *(const bf16x8*)(p + m * 1024);
}
__device__ __forceinline__ void rdB4(bf16x8 (&d)[4], const char* p) {
#pragma unroll
  for (int n = 0; n < 4; n++) d[n] = *(const bf16x8*)(p + n * 1024);
}
__device__ __forceinline__ void mm44(f32x4 (&acc)[4][4], const bf16x8 (&A_)[4],
                                     const bf16x8 (&B_)[4]) {
  __builtin_amdgcn_s_setprio(1);
#pragma unroll
  for (int m = 0; m < 4; m++)
#pragma unroll
    for (int n = 0; n < 4; n++)
      acc[m][n] = mfma16(A_[m], B_[n], acc[m][n]);
  __builtin_amdgcn_s_setprio(0);
}

template <typename OutT>
__global__ __launch_bounds__(512, 2) void k_gemm8b(const __hip_bfloat16* __restrict__ A,
    const __hip_bfloat16* __restrict__ Bt, OutT* __restrict__ Co,
    int M, int N) {
  constexpr int K = 2048;
  __shared__ __align__(16) char lds[147456];          // 3 x 48KB ring
  const int nbx = M >> 7;                              // 128-row tiles
  const int nwg = nbx * (N >> 8);                      // %8==0 for our shapes
  const int wg = blockIdx.x;
  const int swz = (wg & 7) * (nwg >> 3) + (wg >> 3);
  const int bx = swz % nbx, by = swz / nbx;
  const int tid = threadIdx.x, lane = tid & 63, wid = tid >> 6;
  const int wr = wid >> 2, wc = wid & 3;
  const int lr = lane & 15, lg = lane >> 4;
  const int roff = lr * 64 + (lg ^ ((lr >> 1) & 3)) * 16;
  // staging: 4 threads/row, thread covers row srow (A; B also srow+128)
  const int srow = wid * 16 + (lane >> 2);             // [0,128)
  const int scol = (((lane & 3) ^ ((srow >> 1) & 3)) << 3);
  const __hip_bfloat16* Ag = A + (size_t)(bx * 128 + srow) * K + scol;
  const __hip_bfloat16* Bg = Bt + (size_t)(by * 256 + srow) * K + scol;
  char* ldsw = lds + wid * 1024;
  const size_t rstepB = (size_t)128 * K;
  // read bases (add bufR + kk-offset + m/n*1024)
  const char* Ab = lds + wr * 4096 + roff;             // A: + kk*8192
  const char* Bb = lds + 16384 + wc * 4096 + roff;     // B: + kk*16384

#define STG_A(bufo, t, kk) gload16(Ag + (t) * 64 + (kk) * 32, \
                                   ldsw + (bufo) + (kk) * 8192)
#define STG_B(bufo, t, kk) { const __hip_bfloat16* g_ = Bg + (t) * 64 + (kk) * 32; \
    gload16(g_, ldsw + (bufo) + 16384 + (kk) * 16384);                              \
    gload16(g_ + rstepB, ldsw + (bufo) + 16384 + (kk) * 16384 + 8192); }
#define BARRIER __builtin_amdgcn_s_barrier()
#define VW6 asm volatile("s_waitcnt vmcnt(6)" ::: "memory")
#define VW0 asm volatile("s_waitcnt vmcnt(0)" ::: "memory")
#define LGKM0 asm volatile("s_waitcnt lgkmcnt(0)" ::: "memory")
#define SB0 __builtin_amdgcn_sched_barrier(0)

  f32x4 acc[4][4];
#pragma unroll
  for (int m = 0; m < 4; m++)
#pragma unroll
    for (int n = 0; n < 4; n++) acc[m][n] = f32x4{0.f, 0.f, 0.f, 0.f};
  bf16x8 rA[4], rB[4];

// TILE(RB = read-buf offset, SB = stage-buf offset, TS = stage src tile,
//      DOSTG, ENDW = end-of-tile vm wait)
#define TILE(RB, SB, TS, DOSTG, ENDW)                                   \
  {                                                                     \
    rdA4(rA, Ab + (RB));                                                \
    rdB4(rB, Bb + (RB));                                                \
    if (DOSTG) { STG_A((SB), (TS), 0); STG_B((SB), (TS), 0); }          \
    BARRIER; LGKM0; SB0;                                                \
    mm44(acc, rA, rB);                                                  \
    BARRIER;                                                            \
    rdA4(rA, Ab + (RB) + 8192);                                         \
    rdB4(rB, Bb + (RB) + 16384);                                        \
    if (DOSTG) { STG_A((SB), (TS), 1); STG_B((SB), (TS), 1); }          \
    BARRIER; LGKM0; SB0;                                                \
    mm44(acc, rA, rB);                                                  \
    ENDW;                                                               \
    BARRIER;                                                            \
  }

  // prologue: stage tiles 0,1 into bufs 0,1
  STG_A(0, 0, 0); STG_B(0, 0, 0); STG_A(0, 0, 1); STG_B(0, 0, 1);
  STG_A(49152, 1, 0); STG_B(49152, 1, 0); STG_A(49152, 1, 1); STG_B(49152, 1, 1);
  VW6;          // tile0's 6 landed; tile1's may be in flight
  BARRIER;

  for (int i = 0; i < 10; ++i) {
    const int t = 3 * i;
    TILE(0,     98304, t + 2, 1, VW6);   // tile 3i   (buf0) stages -> buf2
    TILE(49152, 0,     t + 3, 1, VW6);   // tile 3i+1 (buf1) stages -> buf0
    TILE(98304, 49152, t + 4, 1, VW6);   // tile 3i+2 (buf2) stages -> buf1
  }
  TILE(0,     0, 0, 0, VW0);             // tile 30 (buf0), drain tile31
  TILE(49152, 0, 0, 0, (void)0);         // tile 31 (buf1)
#undef TILE
#undef STG_A
#undef STG_B

  const int row0 = bx * 128 + wr * 64 + lg * 4;
  const int col0 = by * 256 + wc * 64 + lr;
#pragma unroll
  for (int m = 0; m < 4; m++)
#pragma unroll
    for (int n = 0; n < 4; n++) {
      size_t base = (size_t)(row0 + m * 16) * N + col0 + n * 16;
#pragma unroll
      for (int r = 0; r < 4; r++) {
        float v = acc[m][n][r];
        if constexpr (sizeof(OutT) == 2)
          Co[base + (size_t)r * N] = __float2bfloat16(v);
        else
          Co[base + (size_t)r * N] = v;
      }
    }
}

// ---------------- in-place QK RMSNorm over head dim (D=128) ----------------
__global__ __launch_bounds__(256) void k_qkrms(__hip_bfloat16* __restrict__ QKV,
    const float* __restrict__ qw, const float* __restrict__ kw) {
  int bt = blockIdx.x;
  int w = threadIdx.x >> 6, lane = threadIdx.x & 63;
  int hv = blockIdx.y * 4 + w;
  const float* wt; int col; float extra;
  if (hv < 16) { wt = qw; col = hv * Dc;             extra = QSCALE; }
  else         { wt = kw; col = Cc + (hv - 16) * Dc; extra = 1.0f;   }
  __hip_bfloat16* p = QKV + (size_t)bt * NQ + col + lane * 2;
  float x0 = __bfloat162float(p[0]);
  float x1 = __bfloat162float(p[1]);
  float ss = x0 * x0 + x1 * x1;
  for (int m = 1; m < 64; m <<= 1) ss += __shfl_xor(ss, m);
  float sc = rsqrtf(ss * (1.0f / Dc) + EPSc) * extra;
  p[0] = __float2bfloat16(x0 * sc * wt[lane * 2]);
  p[1] = __float2bfloat16(x1 * sc * wt[lane * 2 + 1]);
}

// ---------------- V transpose: (b,t,h,d) cols of QKV -> Vt (b,h,d,t) -------
__global__ __launch_bounds__(256) void k_vtrans(const __hip_bfloat16* __restrict__ QKV,
                                                __hip_bfloat16* __restrict__ Vt) {
  __shared__ __hip_bfloat16 tile[64][65];
  int bh = blockIdx.z, t0 = blockIdx.x * 64, d0 = blockIdx.y * 64;
  int b = bh >> 4, h = bh & 15;
  int c = threadIdx.x & 63, rb = threadIdx.x >> 6;
  for (int i = 0; i < 16; i++) {
    int r = rb * 16 + i;
    tile[r][c] = QKV[(size_t)(b * Tc + t0 + r) * NQ + 2 * Cc + h * Dc + d0 + c];
  }
  __syncthreads();
  for (int i = 0; i < 16; i++) {
    int r = rb * 16 + i;
    Vt[((size_t)bh * Dc + d0 + r) * Tc + t0 + c] = tile[c][r];
  }
}

// ---------------- flash attention v2: LDS-staged K/V, dbuf, paired tiles ---
// grid (bh=32, pp=16); 4 waves; block handles q-tiles {31-pp, pp} (64 rows each)
__global__ __launch_bounds__(256, 2) void k_attn(const __hip_bfloat16* __restrict__ QKV,
    const __hip_bfloat16* __restrict__ Vt, const float* __restrict__ subw,
    __hip_bfloat16* __restrict__ Y) {
  __shared__ __align__(16) __hip_bfloat16 Ks[2][64][128];   // 32 KB
  __shared__ __align__(16) __hip_bfloat16 Vs[2][128][64];   // 32 KB
  __shared__ __align__(16) __hip_bfloat16 Plds[4][16][72];  // 9 KB (padded stride 144B)
  const int bh = blockIdx.x, pp = blockIdx.y;
  const int b = bh >> 4, h = bh & 15;
  const int w = threadIdx.x >> 6, lane = threadIdx.x & 63;
  const int lr = lane & 15, lg = lane >> 4;
  const float slope = exp2f(-0.5f * (float)(h + 1));
  const __hip_bfloat16* Kbase = QKV + (size_t)b * Tc * NQ + Cc + h * Dc;
  const __hip_bfloat16* Vbase = Vt + (size_t)bh * Dc * Tc;
  const int krow = (lane >> 4);
  const int kcolb = ((lane & 15) << 4);
  const int vrow = (lane >> 3);
  const int vcolb = ((lane & 7) << 4);
  f32x4 zero = {0.f, 0.f, 0.f, 0.f};

  int buf = 0;
  for (int ti = 0; ti < 2; ti++) {
    const int qt = (ti == 0) ? (31 - pp) : pp;
    const int q0 = qt * 64 + w * 16;
    const int nchunk = qt + 1;
    bf16x8 aq[4];
    {
      const __hip_bfloat16* qb = QKV + (size_t)(b * Tc + q0 + lr) * NQ + h * Dc + lg * 8;
      for (int c = 0; c < 4; c++) aq[c] = *(const bf16x8*)(qb + c * 32);
    }
    f32x4 acc[8];
    for (int d = 0; d < 8; d++) acc[d] = zero;
    float mrow[4] = {-1e30f, -1e30f, -1e30f, -1e30f};
    float lrow[4] = {0.f, 0.f, 0.f, 0.f};

#define STAGE(bb, t)                                                              \
    {                                                                             \
      const int s0_ = (t) * 64;                                                   \
      for (int j = 0; j < 4; j++) {                                               \
        int row = w * 16 + j * 4 + krow;                                          \
        int cb = kcolb ^ ((row & 7) << 4);                                        \
        gload16(Kbase + (size_t)(s0_ + row) * NQ + (cb >> 1),                     \
                &Ks[bb][w * 16 + j * 4][0]);                                      \
      }                                                                           \
      for (int j = 0; j < 4; j++) {                                               \
        int row = w * 32 + j * 8 + vrow;                                          \
        int cb = vcolb ^ ((row & 7) << 4);                                        \
        gload16(Vbase + (size_t)row * Tc + s0_ + (cb >> 1),                       \
                &Vs[bb][w * 32 + j * 8][0]);                                      \
      }                                                                           \
    }

    STAGE(buf, 0);
    __syncthreads();
    for (int t = 0; t < nchunk; t++) {
      if (t + 1 < nchunk) STAGE(buf ^ 1, t + 1);
      const int s0 = t * 64;
      f32x4 s[4];
      for (int ss = 0; ss < 4; ss++) s[ss] = zero;
      __builtin_amdgcn_s_setprio(1);
      for (int c = 0; c < 4; c++)
        for (int ss = 0; ss < 4; ss++) {
          int kr = ss * 16 + lr;
          const bf16x8 kf = *(const bf16x8*)
              &Ks[buf][kr][((c * 64 + lg * 16) ^ ((kr & 7) << 4)) >> 1];
          s[ss] = mfma16(aq[c], kf, s[ss]);
        }
      __builtin_amdgcn_s_setprio(0);
      float ps[4][4], mt[4];
      for (int r = 0; r < 4; r++) mt[r] = -1e30f;
      for (int ss = 0; ss < 4; ss++) {
        int jj = s0 + ss * 16 + lr;
        for (int r = 0; r < 4; r++) {
          int i = q0 + lg * 4 + r;
          float pv = (jj <= i) ? s[ss][r] - slope * (float)(i - jj) : -1e30f;
          ps[ss][r] = pv;
          mt[r] = fmaxf(mt[r], pv);
        }
      }
      for (int m = 1; m < 16; m <<= 1)
        for (int r = 0; r < 4; r++) mt[r] = fmaxf(mt[r], __shfl_xor(mt[r], m));
      float corr[4], rs[4];
      for (int r = 0; r < 4; r++) {
        float mn = fmaxf(mrow[r], mt[r]);
        corr[r] = __expf(mrow[r] - mn);
        mrow[r] = mn;
        rs[r] = 0.f;
      }
      for (int ss = 0; ss < 4; ss++)
        for (int r = 0; r < 4; r++) {
          float e = __expf(ps[ss][r] - mrow[r]);
          ps[ss][r] = e;
          rs[r] += e;
        }
      for (int m = 1; m < 16; m <<= 1)
        for (int r = 0; r < 4; r++) rs[r] += __shfl_xor(rs[r], m);
      for (int r = 0; r < 4; r++) lrow[r] = lrow[r] * corr[r] + rs[r];
      for (int d = 0; d < 8; d++)
        for (int r = 0; r < 4; r++) acc[d][r] *= corr[r];
      for (int ss = 0; ss < 4; ss++)
        for (int r = 0; r < 4; r++)
          Plds[w][lg * 4 + r][ss * 16 + lr] = __float2bfloat16(ps[ss][r]);
      bf16x8 pa0 = *(const bf16x8*)&Plds[w][lr][lg * 8];
      bf16x8 pa1 = *(const bf16x8*)&Plds[w][lr][32 + lg * 8];
      __builtin_amdgcn_s_setprio(1);
      for (int d = 0; d < 8; d++) {
        int vr = d * 16 + lr;
        const bf16x8 b0 = *(const bf16x8*)
            &Vs[buf][vr][((lg * 16) ^ ((vr & 7) << 4)) >> 1];
        const bf16x8 b1 = *(const bf16x8*)
            &Vs[buf][vr][((64 + lg * 16) ^ ((vr & 7) << 4)) >> 1];
        acc[d] = mfma16(pa0, b0, acc[d]);
        acc[d] = mfma16(pa1, b1, acc[d]);
      }
      __builtin_amdgcn_s_setprio(0);
      __syncthreads();
      buf ^= 1;
    }
#undef STAGE
    float ssum[4] = {0.f, 0.f, 0.f, 0.f};
    for (int r = 0; r < 4; r++) {
      float rl = 1.0f / lrow[r];
      for (int d = 0; d < 8; d++) {
        float o = acc[d][r] * rl;
        acc[d][r] = o;
        ssum[r] += o * o;
      }
    }
    for (int m = 1; m < 16; m <<= 1)
      for (int r = 0; r < 4; r++) ssum[r] += __shfl_xor(ssum[r], m);
    float ms[4];
    for (int r = 0; r < 4; r++) ms[r] = rsqrtf(ssum[r] * (1.0f / Dc) + EPSc);
    for (int d = 0; d < 8; d++) {
      float wv = subw[d * 16 + lr];
      for (int r = 0; r < 4; r++) {
        float y = acc[d][r] * ms[r] * wv;
        Y[(size_t)(b * Tc + q0 + lg * 4 + r) * Cc + h * Dc + d * 16 + lr] =
            __float2bfloat16(y);
      }
    }
  }
}

extern "C" void kernel_launch(void* const* d_in, const int* in_sizes, int n_in,
                              void* d_out, int out_size, void* d_ws, size_t ws_size,
                              hipStream_t stream) {
  const float* x  = (const float*)d_in[0];
  const float* Wq = (const float*)d_in[1];
  const float* Wk = (const float*)d_in[2];
  const float* Wv = (const float*)d_in[3];
  const float* Wp = (const float*)d_in[4];
  const float* qw = (const float*)d_in[5];
  const float* kw = (const float*)d_in[6];
  const float* sw = (const float*)d_in[7];
  float* out = (float*)d_out;

  char* ws = (char*)d_ws;
  __hip_bfloat16* Xb    = (__hip_bfloat16*)(ws + 0);          // 16 MiB (4096x2048)
  __hip_bfloat16* Wqkv  = (__hip_bfloat16*)(ws + 16777216);   // 24 MiB (6144x2048, N-major)
  __hip_bfloat16* Wproj = (__hip_bfloat16*)(ws + 41943040);   //  8 MiB (2048x2048, N-major)
  __hip_bfloat16* QKV   = (__hip_bfloat16*)(ws + 50331648);   // 48 MiB (4096x6144)
  __hip_bfloat16* Vt    = (__hip_bfloat16*)(ws + 100663296);  // 16 MiB (b,h,d,t)
  __hip_bfloat16* Yb    = (__hip_bfloat16*)(ws + 117440512);  // 16 MiB (4096x2048)

  k_xconv<<<dim3((BTc * Cc) / 1024), 256, 0, stream>>>(x, Xb);
  k_wconv<<<dim3(32, 32, 4), 256, 0, stream>>>(Wq, Wk, Wv, Wp, Wqkv, Wproj);
  // QKV: 128x256 tiles -> 32x24 = 768 wgs = 3.0/CU exact (no tail)
  k_gemm8b<__hip_bfloat16><<<dim3((BTc / 128) * (NQ / 256)), 512, 0, stream>>>(
      Xb, Wqkv, QKV, BTc, NQ);
  k_qkrms<<<dim3(BTc, 8), 256, 0, stream>>>(QKV, qw, kw);
  k_vtrans<<<dim3(Tc / 64, Dc / 64, Bc * Hc), 256, 0, stream>>>(QKV, Vt);
  k_attn<<<dim3(Bc * Hc, 16), 256, 0, stream>>>(QKV, Vt, sw, Yb);
  // proj: 128x256 tiles -> 32x8 = 256 wgs = 1.0/CU exact
  k_gemm8b<float><<<dim3((BTc / 128) * (Cc / 256)), 512, 0, stream>>>(
      Yb, Wproj, out, BTc, Cc);
}

// Round 10
// 294.552 us; speedup vs baseline: 1.0208x; 1.0020x over previous
//
#include <hip/hip_runtime.h>
#include <hip/hip_bf16.h>

// Problem constants
#define Bc 2
#define Tc 2048
#define Cc 2048
#define Hc 16
#define Dc 128
#define BTc 4096
#define NQ 6144            // 3*Cc
#define EPSc 1e-5f
#define QSCALE 0.08838834764831845f   // 1/sqrt(128)

typedef __attribute__((ext_vector_type(8))) short bf16x8;
typedef __attribute__((ext_vector_type(4))) short bf16x4;
typedef __attribute__((ext_vector_type(4))) float f32x4;

__device__ __forceinline__ f32x4 mfma16(bf16x8 a, bf16x8 b, f32x4 c) {
  return __builtin_amdgcn_mfma_f32_16x16x32_bf16(a, b, c, 0, 0, 0);
}

__device__ __forceinline__ void gload16(const void* g, void* l) {
  __builtin_amdgcn_global_load_lds(
      (const __attribute__((address_space(1))) void*)g,
      (__attribute__((address_space(3))) void*)l, 16, 0, 0);
}

// ---------------- fp32 -> bf16 convert (x) ----------------
__global__ __launch_bounds__(256) void k_xconv(const float* __restrict__ x,
                                               __hip_bfloat16* __restrict__ xb) {
  size_t i = ((size_t)blockIdx.x * 256 + threadIdx.x) * 4;
  float4 v = *(const float4*)(x + i);
  union { __hip_bfloat16 h[4]; bf16x4 v4; } u;
  u.h[0] = __float2bfloat16(v.x); u.h[1] = __float2bfloat16(v.y);
  u.h[2] = __float2bfloat16(v.z); u.h[3] = __float2bfloat16(v.w);
  *(bf16x4*)(xb + i) = u.v4;
}

// ------- weight transpose+convert: W (K x N) fp32 -> Wt (N x K) bf16 -------
__global__ __launch_bounds__(256) void k_wconv(const float* __restrict__ Wq,
    const float* __restrict__ Wk, const float* __restrict__ Wv,
    const float* __restrict__ Wp, __hip_bfloat16* __restrict__ Wqkv_t,
    __hip_bfloat16* __restrict__ Wproj_t) {
  __shared__ float tile[64][65];
  int z = blockIdx.z;
  const float* src = (z == 0) ? Wq : (z == 1) ? Wk : (z == 2) ? Wv : Wp;
  __hip_bfloat16* dst = (z < 3) ? (Wqkv_t + (size_t)z * Cc * Cc) : Wproj_t;
  int k0 = blockIdx.x * 64, n0 = blockIdx.y * 64;
  int c = threadIdx.x & 63, rb = threadIdx.x >> 6;
  for (int i = 0; i < 16; i++) {
    int r = rb * 16 + i;
    tile[r][c] = src[(size_t)(k0 + r) * Cc + n0 + c];
  }
  __syncthreads();
  for (int i = 0; i < 16; i++) {
    int r = rb * 16 + i;
    dst[(size_t)(n0 + r) * Cc + k0 + c] = __float2bfloat16(tile[c][r]);
  }
}

// ============ 128x256-tile 8-phase GEMM (ring-3), B pre-transposed =========
// No explicit lgkmcnt(0)/sched_barrier before MFMA — the compiler's counted
// lgkm waits interleave LDS service with the MFMA cluster.
__device__ __forceinline__ void rdA4(bf16x8 (&d)[4], const char* p) {
#pragma unroll
  for (int m = 0; m < 4; m++) d[m] = *(const bf16x8*)(p + m * 1024);
}
__device__ __forceinline__ void rdB4(bf16x8 (&d)[4], const char* p) {
#pragma unroll
  for (int n = 0; n < 4; n++) d[n] = *(const bf16x8*)(p + n * 1024);
}
__device__ __forceinline__ void mm44(f32x4 (&acc)[4][4], const bf16x8 (&A_)[4],
                                     const bf16x8 (&B_)[4]) {
  __builtin_amdgcn_s_setprio(1);
#pragma unroll
  for (int m = 0; m < 4; m++)
#pragma unroll
    for (int n = 0; n < 4; n++)
      acc[m][n] = mfma16(A_[m], B_[n], acc[m][n]);
  __builtin_amdgcn_s_setprio(0);
}

template <typename OutT>
__global__ __launch_bounds__(512, 2) void k_gemm8b(const __hip_bfloat16* __restrict__ A,
    const __hip_bfloat16* __restrict__ Bt, OutT* __restrict__ Co,
    int M, int N) {
  constexpr int K = 2048;
  __shared__ __align__(16) char lds[147456];          // 3 x 48KB ring
  const int nbx = M >> 7;                              // 128-row tiles
  const int nwg = nbx * (N >> 8);                      // %8==0 for our shapes
  const int wg = blockIdx.x;
  const int swz = (wg & 7) * (nwg >> 3) + (wg >> 3);
  const int bx = swz % nbx, by = swz / nbx;
  const int tid = threadIdx.x, lane = tid & 63, wid = tid >> 6;
  const int wr = wid >> 2, wc = wid & 3;
  const int lr = lane & 15, lg = lane >> 4;
  const int roff = lr * 64 + (lg ^ ((lr >> 1) & 3)) * 16;
  const int srow = wid * 16 + (lane >> 2);             // [0,128)
  const int scol = (((lane & 3) ^ ((srow >> 1) & 3)) << 3);
  const __hip_bfloat16* Ag = A + (size_t)(bx * 128 + srow) * K + scol;
  const __hip_bfloat16* Bg = Bt + (size_t)(by * 256 + srow) * K + scol;
  char* ldsw = lds + wid * 1024;
  const size_t rstepB = (size_t)128 * K;
  const char* Ab = lds + wr * 4096 + roff;             // A: + kk*8192
  const char* Bb = lds + 16384 + wc * 4096 + roff;     // B: + kk*16384

#define STG_A(bufo, t, kk) gload16(Ag + (t) * 64 + (kk) * 32, \
                                   ldsw + (bufo) + (kk) * 8192)
#define STG_B(bufo, t, kk) { const __hip_bfloat16* g_ = Bg + (t) * 64 + (kk) * 32; \
    gload16(g_, ldsw + (bufo) + 16384 + (kk) * 16384);                              \
    gload16(g_ + rstepB, ldsw + (bufo) + 16384 + (kk) * 16384 + 8192); }
#define BARRIER asm volatile("s_barrier" ::: "memory")
#define VW6 asm volatile("s_waitcnt vmcnt(6)" ::: "memory")
#define VW0 asm volatile("s_waitcnt vmcnt(0)" ::: "memory")

  f32x4 acc[4][4];
#pragma unroll
  for (int m = 0; m < 4; m++)
#pragma unroll
    for (int n = 0; n < 4; n++) acc[m][n] = f32x4{0.f, 0.f, 0.f, 0.f};
  bf16x8 rA[4], rB[4];

#define TILE(RB, SB, TS, DOSTG, ENDW)                                   \
  {                                                                     \
    rdA4(rA, Ab + (RB));                                                \
    rdB4(rB, Bb + (RB));                                                \
    if (DOSTG) { STG_A((SB), (TS), 0); STG_B((SB), (TS), 0); }          \
    BARRIER;                                                            \
    mm44(acc, rA, rB);                                                  \
    BARRIER;                                                            \
    rdA4(rA, Ab + (RB) + 8192);                                         \
    rdB4(rB, Bb + (RB) + 16384);                                        \
    if (DOSTG) { STG_A((SB), (TS), 1); STG_B((SB), (TS), 1); }          \
    BARRIER;                                                            \
    mm44(acc, rA, rB);                                                  \
    ENDW;                                                               \
    BARRIER;                                                            \
  }

  // prologue: stage tiles 0,1 into bufs 0,1
  STG_A(0, 0, 0); STG_B(0, 0, 0); STG_A(0, 0, 1); STG_B(0, 0, 1);
  STG_A(49152, 1, 0); STG_B(49152, 1, 0); STG_A(49152, 1, 1); STG_B(49152, 1, 1);
  VW6;
  BARRIER;

  for (int i = 0; i < 10; ++i) {
    const int t = 3 * i;
    TILE(0,     98304, t + 2, 1, VW6);   // tile 3i   (buf0) stages -> buf2
    TILE(49152, 0,     t + 3, 1, VW6);   // tile 3i+1 (buf1) stages -> buf0
    TILE(98304, 49152, t + 4, 1, VW6);   // tile 3i+2 (buf2) stages -> buf1
  }
  TILE(0,     0, 0, 0, VW0);             // tile 30 (buf0), drain tile31
  TILE(49152, 0, 0, 0, (void)0);         // tile 31 (buf1)
#undef TILE
#undef STG_A
#undef STG_B
#undef BARRIER
#undef VW6
#undef VW0

  const int row0 = bx * 128 + wr * 64 + lg * 4;
  const int col0 = by * 256 + wc * 64 + lr;
#pragma unroll
  for (int m = 0; m < 4; m++)
#pragma unroll
    for (int n = 0; n < 4; n++) {
      size_t base = (size_t)(row0 + m * 16) * N + col0 + n * 16;
#pragma unroll
      for (int r = 0; r < 4; r++) {
        float v = acc[m][n][r];
        if constexpr (sizeof(OutT) == 2)
          Co[base + (size_t)r * N] = __float2bfloat16(v);
        else
          Co[base + (size_t)r * N] = v;
      }
    }
}

// ---------------- in-place QK RMSNorm over head dim (D=128) ----------------
// Round-7 numerics: Q gets 1/sqrt(D) folded (no LOG2E).
__global__ __launch_bounds__(256) void k_qkrms(__hip_bfloat16* __restrict__ QKV,
    const float* __restrict__ qw, const float* __restrict__ kw) {
  int bt = blockIdx.x;
  int w = threadIdx.x >> 6, lane = threadIdx.x & 63;
  int hv = blockIdx.y * 4 + w;
  const float* wt; int col; float extra;
  if (hv < 16) { wt = qw; col = hv * Dc;             extra = QSCALE; }
  else         { wt = kw; col = Cc + (hv - 16) * Dc; extra = 1.0f;   }
  __hip_bfloat16* p = QKV + (size_t)bt * NQ + col + lane * 2;
  float x0 = __bfloat162float(p[0]);
  float x1 = __bfloat162float(p[1]);
  float ss = x0 * x0 + x1 * x1;
  for (int m = 1; m < 64; m <<= 1) ss += __shfl_xor(ss, m);
  float sc = rsqrtf(ss * (1.0f / Dc) + EPSc) * extra;
  p[0] = __float2bfloat16(x0 * sc * wt[lane * 2]);
  p[1] = __float2bfloat16(x1 * sc * wt[lane * 2 + 1]);
}

// ---------------- V transpose: (b,t,h,d) cols of QKV -> Vt (b,h,d,t) -------
__global__ __launch_bounds__(256) void k_vtrans(const __hip_bfloat16* __restrict__ QKV,
                                                __hip_bfloat16* __restrict__ Vt) {
  __shared__ __hip_bfloat16 tile[64][65];
  int bh = blockIdx.z, t0 = blockIdx.x * 64, d0 = blockIdx.y * 64;
  int b = bh >> 4, h = bh & 15;
  int c = threadIdx.x & 63, rb = threadIdx.x >> 6;
  for (int i = 0; i < 16; i++) {
    int r = rb * 16 + i;
    tile[r][c] = QKV[(size_t)(b * Tc + t0 + r) * NQ + 2 * Cc + h * Dc + d0 + c];
  }
  __syncthreads();
  for (int i = 0; i < 16; i++) {
    int r = rb * 16 + i;
    Vt[((size_t)bh * Dc + d0 + r) * Tc + t0 + c] = tile[c][r];
  }
}

// ---------------- flash attention: counted-vmcnt pipeline, ROUND-7 softmax -
// grid (bh=32, pp=16); 4 waves; block handles q-tiles {31-pp, pp}.
// Pipeline (kept from r8): STAGE(t+1); vmcnt(8); barrier; compute;
// lgkmcnt(0); barrier.  Softmax math is byte-identical to round 7 (passed).
__global__ __launch_bounds__(256, 2) void k_attn(const __hip_bfloat16* __restrict__ QKV,
    const __hip_bfloat16* __restrict__ Vt, const float* __restrict__ subw,
    __hip_bfloat16* __restrict__ Y) {
  __shared__ __align__(16) __hip_bfloat16 Ks[2][64][128];   // 32 KB
  __shared__ __align__(16) __hip_bfloat16 Vs[2][128][64];   // 32 KB
  __shared__ __align__(16) __hip_bfloat16 Plds[4][16][72];  // 9 KB
  const int bh = blockIdx.x, pp = blockIdx.y;
  const int b = bh >> 4, h = bh & 15;
  const int w = threadIdx.x >> 6, lane = threadIdx.x & 63;
  const int lr = lane & 15, lg = lane >> 4;
  const float slope = exp2f(-0.5f * (float)(h + 1));
  const __hip_bfloat16* Kbase = QKV + (size_t)b * Tc * NQ + Cc + h * Dc;
  const __hip_bfloat16* Vbase = Vt + (size_t)bh * Dc * Tc;
  const int krow = (lane >> 4);
  const int kcolb = ((lane & 15) << 4);
  const int vrow = (lane >> 3);
  const int vcolb = ((lane & 7) << 4);
  f32x4 zero = {0.f, 0.f, 0.f, 0.f};

#define STAGE(bb, t)                                                              \
    {                                                                             \
      const int s0_ = (t) * 64;                                                   \
      for (int j = 0; j < 4; j++) {                                               \
        int row = w * 16 + j * 4 + krow;                                          \
        int cb = kcolb ^ ((row & 7) << 4);                                        \
        gload16(Kbase + (size_t)(s0_ + row) * NQ + (cb >> 1),                     \
                &Ks[bb][w * 16 + j * 4][0]);                                      \
      }                                                                           \
      for (int j = 0; j < 4; j++) {                                               \
        int row = w * 32 + j * 8 + vrow;                                          \
        int cb = vcolb ^ ((row & 7) << 4);                                        \
        gload16(Vbase + (size_t)row * Tc + s0_ + (cb >> 1),                       \
                &Vs[bb][w * 32 + j * 8][0]);                                      \
      }                                                                           \
    }
#define SBAR asm volatile("s_barrier" ::: "memory")
#define AVW8 asm volatile("s_waitcnt vmcnt(8)" ::: "memory")
#define AVW0 asm volatile("s_waitcnt vmcnt(0)" ::: "memory")
#define ALG0 asm volatile("s_waitcnt lgkmcnt(0)" ::: "memory")

  int buf = 0;
  for (int ti = 0; ti < 2; ti++) {
    const int qt = (ti == 0) ? (31 - pp) : pp;
    const int q0 = qt * 64 + w * 16;
    const int nchunk = qt + 1;
    bf16x8 aq[4];
    {
      const __hip_bfloat16* qb = QKV + (size_t)(b * Tc + q0 + lr) * NQ + h * Dc + lg * 8;
      for (int c = 0; c < 4; c++) aq[c] = *(const bf16x8*)(qb + c * 32);
    }
    f32x4 acc[8];
    for (int d = 0; d < 8; d++) acc[d] = zero;
    float mrow[4] = {-1e30f, -1e30f, -1e30f, -1e30f};
    float lrow[4] = {0.f, 0.f, 0.f, 0.f};

    SBAR;                    // protect K/V buffers vs previous q-tile readers
    STAGE(buf, 0);
    for (int t = 0; t < nchunk; t++) {
      if (t + 1 < nchunk) { STAGE(buf ^ 1, t + 1); AVW8; }
      else                { AVW0; }
      SBAR;
      const int s0 = t * 64;
      // ---- QK^T (16 MFMA) ----
      f32x4 s[4];
      for (int ss = 0; ss < 4; ss++) s[ss] = zero;
      __builtin_amdgcn_s_setprio(1);
      for (int c = 0; c < 4; c++)
        for (int ss = 0; ss < 4; ss++) {
          int kr = ss * 16 + lr;
          const bf16x8 kf = *(const bf16x8*)
              &Ks[buf][kr][((c * 64 + lg * 16) ^ ((kr & 7) << 4)) >> 1];
          s[ss] = mfma16(aq[c], kf, s[ss]);
        }
      __builtin_amdgcn_s_setprio(0);
      // ---- softmax (online) — round-7 math verbatim ----
      float ps[4][4], mt[4];
      for (int r = 0; r < 4; r++) mt[r] = -1e30f;
      for (int ss = 0; ss < 4; ss++) {
        int jj = s0 + ss * 16 + lr;
        for (int r = 0; r < 4; r++) {
          int i = q0 + lg * 4 + r;
          float pv = (jj <= i) ? s[ss][r] - slope * (float)(i - jj) : -1e30f;
          ps[ss][r] = pv;
          mt[r] = fmaxf(mt[r], pv);
        }
      }
      for (int m = 1; m < 16; m <<= 1)
        for (int r = 0; r < 4; r++) mt[r] = fmaxf(mt[r], __shfl_xor(mt[r], m));
      float corr[4], rs[4];
      for (int r = 0; r < 4; r++) {
        float mn = fmaxf(mrow[r], mt[r]);
        corr[r] = __expf(mrow[r] - mn);
        mrow[r] = mn;
        rs[r] = 0.f;
      }
      for (int ss = 0; ss < 4; ss++)
        for (int r = 0; r < 4; r++) {
          float e = __expf(ps[ss][r] - mrow[r]);
          ps[ss][r] = e;
          rs[r] += e;
        }
      for (int m = 1; m < 16; m <<= 1)
        for (int r = 0; r < 4; r++) rs[r] += __shfl_xor(rs[r], m);
      for (int r = 0; r < 4; r++) lrow[r] = lrow[r] * corr[r] + rs[r];
      for (int d = 0; d < 8; d++)
        for (int r = 0; r < 4; r++) acc[d][r] *= corr[r];
      // ---- P -> LDS, PV (16 MFMA) ----
      for (int ss = 0; ss < 4; ss++)
        for (int r = 0; r < 4; r++)
          Plds[w][lg * 4 + r][ss * 16 + lr] = __float2bfloat16(ps[ss][r]);
      bf16x8 pa0 = *(const bf16x8*)&Plds[w][lr][lg * 8];
      bf16x8 pa1 = *(const bf16x8*)&Plds[w][lr][32 + lg * 8];
      __builtin_amdgcn_s_setprio(1);
      for (int d = 0; d < 8; d++) {
        int vr = d * 16 + lr;
        const bf16x8 b0 = *(const bf16x8*)
            &Vs[buf][vr][((lg * 16) ^ ((vr & 7) << 4)) >> 1];
        const bf16x8 b1 = *(const bf16x8*)
            &Vs[buf][vr][((64 + lg * 16) ^ ((vr & 7) << 4)) >> 1];
        acc[d] = mfma16(pa0, b0, acc[d]);
        acc[d] = mfma16(pa1, b1, acc[d]);
      }
      __builtin_amdgcn_s_setprio(0);
      ALG0; SBAR;            // reads of buf done before next overwrite
      buf ^= 1;
    }
    // ---- epilogue (round-7): 1/l, subln rmsnorm, store ----
    float ssum[4] = {0.f, 0.f, 0.f, 0.f};
    for (int r = 0; r < 4; r++) {
      float rl = 1.0f / lrow[r];
      for (int d = 0; d < 8; d++) {
        float o = acc[d][r] * rl;
        acc[d][r] = o;
        ssum[r] += o * o;
      }
    }
    for (int m = 1; m < 16; m <<= 1)
      for (int r = 0; r < 4; r++) ssum[r] += __shfl_xor(ssum[r], m);
    float ms[4];
    for (int r = 0; r < 4; r++) ms[r] = rsqrtf(ssum[r] * (1.0f / Dc) + EPSc);
    for (int d = 0; d < 8; d++) {
      float wv = subw[d * 16 + lr];
      for (int r = 0; r < 4; r++) {
        float y = acc[d][r] * ms[r] * wv;
        Y[(size_t)(b * Tc + q0 + lg * 4 + r) * Cc + h * Dc + d * 16 + lr] =
            __float2bfloat16(y);
      }
    }
  }
#undef STAGE
#undef SBAR
#undef AVW8
#undef AVW0
#undef ALG0
}

extern "C" void kernel_launch(void* const* d_in, const int* in_sizes, int n_in,
                              void* d_out, int out_size, void* d_ws, size_t ws_size,
                              hipStream_t stream) {
  const float* x  = (const float*)d_in[0];
  const float* Wq = (const float*)d_in[1];
  const float* Wk = (const float*)d_in[2];
  const float* Wv = (const float*)d_in[3];
  const float* Wp = (const float*)d_in[4];
  const float* qw = (const float*)d_in[5];
  const float* kw = (const float*)d_in[6];
  const float* sw = (const float*)d_in[7];
  float* out = (float*)d_out;

  char* ws = (char*)d_ws;
  __hip_bfloat16* Xb    = (__hip_bfloat16*)(ws + 0);          // 16 MiB (4096x2048)
  __hip_bfloat16* Wqkv  = (__hip_bfloat16*)(ws + 16777216);   // 24 MiB (6144x2048, N-major)
  __hip_bfloat16* Wproj = (__hip_bfloat16*)(ws + 41943040);   //  8 MiB (2048x2048, N-major)
  __hip_bfloat16* QKV   = (__hip_bfloat16*)(ws + 50331648);   // 48 MiB (4096x6144)
  __hip_bfloat16* Vt    = (__hip_bfloat16*)(ws + 100663296);  // 16 MiB (b,h,d,t)
  __hip_bfloat16* Yb    = (__hip_bfloat16*)(ws + 117440512);  // 16 MiB (4096x2048)

  k_xconv<<<dim3((BTc * Cc) / 1024), 256, 0, stream>>>(x, Xb);
  k_wconv<<<dim3(32, 32, 4), 256, 0, stream>>>(Wq, Wk, Wv, Wp, Wqkv, Wproj);
  // QKV: 128x256 tiles -> 768 wgs = 3.0/CU exact
  k_gemm8b<__hip_bfloat16><<<dim3((BTc / 128) * (NQ / 256)), 512, 0, stream>>>(
      Xb, Wqkv, QKV, BTc, NQ);
  k_qkrms<<<dim3(BTc, 8), 256, 0, stream>>>(QKV, qw, kw);
  k_vtrans<<<dim3(Tc / 64, Dc / 64, Bc * Hc), 256, 0, stream>>>(QKV, Vt);
  k_attn<<<dim3(Bc * Hc, 16), 256, 0, stream>>>(QKV, Vt, sw, Yb);
  // proj: 128x256 tiles -> 256 wgs = 1.0/CU exact
  k_gemm8b<float><<<dim3((BTc / 128) * (Cc / 256)), 512, 0, stream>>>(
      Yb, Wproj, out, BTc, Cc);
}

// Round 11
// 279.770 us; speedup vs baseline: 1.0748x; 1.0528x over previous
//
#include <hip/hip_runtime.h>
#include <hip/hip_bf16.h>

// Problem constants
#define Bc 2
#define Tc 2048
#define Cc 2048
#define Hc 16
#define Dc 128
#define BTc 4096
#define NQ 6144            // 3*Cc
#define EPSc 1e-5f
#define QSCALE 0.08838834764831845f   // 1/sqrt(128)

typedef __attribute__((ext_vector_type(8))) short bf16x8;
typedef __attribute__((ext_vector_type(4))) short bf16x4;
typedef __attribute__((ext_vector_type(4))) float f32x4;

__device__ __forceinline__ f32x4 mfma16(bf16x8 a, bf16x8 b, f32x4 c) {
  return __builtin_amdgcn_mfma_f32_16x16x32_bf16(a, b, c, 0, 0, 0);
}

__device__ __forceinline__ void gload16(const void* g, void* l) {
  __builtin_amdgcn_global_load_lds(
      (const __attribute__((address_space(1))) void*)g,
      (__attribute__((address_space(3))) void*)l, 16, 0, 0);
}

// ---------------- fp32 -> bf16 convert (x) ----------------
__global__ __launch_bounds__(256) void k_xconv(const float* __restrict__ x,
                                               __hip_bfloat16* __restrict__ xb) {
  size_t i = ((size_t)blockIdx.x * 256 + threadIdx.x) * 4;
  float4 v = *(const float4*)(x + i);
  union { __hip_bfloat16 h[4]; bf16x4 v4; } u;
  u.h[0] = __float2bfloat16(v.x); u.h[1] = __float2bfloat16(v.y);
  u.h[2] = __float2bfloat16(v.z); u.h[3] = __float2bfloat16(v.w);
  *(bf16x4*)(xb + i) = u.v4;
}

// ------- weight transpose+convert: W (K x N) fp32 -> Wt (N x K) bf16 -------
__global__ __launch_bounds__(256) void k_wconv(const float* __restrict__ Wq,
    const float* __restrict__ Wk, const float* __restrict__ Wv,
    const float* __restrict__ Wp, __hip_bfloat16* __restrict__ Wqkv_t,
    __hip_bfloat16* __restrict__ Wproj_t) {
  __shared__ float tile[64][65];
  int z = blockIdx.z;
  const float* src = (z == 0) ? Wq : (z == 1) ? Wk : (z == 2) ? Wv : Wp;
  __hip_bfloat16* dst = (z < 3) ? (Wqkv_t + (size_t)z * Cc * Cc) : Wproj_t;
  int k0 = blockIdx.x * 64, n0 = blockIdx.y * 64;
  int c = threadIdx.x & 63, rb = threadIdx.x >> 6;
  for (int i = 0; i < 16; i++) {
    int r = rb * 16 + i;
    tile[r][c] = src[(size_t)(k0 + r) * Cc + n0 + c];
  }
  __syncthreads();
  for (int i = 0; i < 16; i++) {
    int r = rb * 16 + i;
    dst[(size_t)(n0 + r) * Cc + k0 + c] = __float2bfloat16(tile[c][r]);
  }
}

// ============ 128x256-tile GEMM, 4 waves of 64x128, BK=32, ring-3 ==========
// C[m][n] = sum_k A[m][k]*Bt[n][k].  256 threads; wave (wr=wid>>1, wc=wid&1)
// owns 64x128 output.  LDS ring of 3 bufs x 24KB (A 8KB @0, B 16KB @8192),
// rows of 64B (32 K-cols), 16B-chunk XOR swizzle chunk^=((row>>1)&3)
// (staging pre-swizzles the GLOBAL column; dest linear, m173).
// Per phase (1 K-tile of 32): 12 ds_read_b128 + 6 gload16 + 32 MFMA +
// vmcnt(6) + 1 barrier.  Tile t reads buf t%3, stages t+2 into (t+2)%3
// (= (t-1)%3, whose reads closed at the previous end barrier).  vmcnt(6)
// leaves exactly tile-(t+2)'s 6 gloads in flight; barrier publishes.
// 72KB LDS -> 2 blocks/CU (8 waves, 2/SIMD).
__device__ __forceinline__ void mm48(f32x4 (&acc)[4][8], const bf16x8 (&A_)[4],
                                     const bf16x8 (&B_)[8]) {
  __builtin_amdgcn_s_setprio(1);
#pragma unroll
  for (int m = 0; m < 4; m++)
#pragma unroll
    for (int n = 0; n < 8; n++)
      acc[m][n] = mfma16(A_[m], B_[n], acc[m][n]);
  __builtin_amdgcn_s_setprio(0);
}

template <typename OutT>
__global__ __launch_bounds__(256, 2) void k_gemm4(const __hip_bfloat16* __restrict__ A,
    const __hip_bfloat16* __restrict__ Bt, OutT* __restrict__ Co,
    int M, int N) {
  constexpr int K = 2048;
  __shared__ __align__(16) char lds[73728];            // 3 x 24KB ring
  const int nbx = M >> 7;                               // 128-row tiles
  const int nwg = nbx * (N >> 8);                       // %8==0
  const int wg = blockIdx.x;
  const int swz = (wg & 7) * (nwg >> 3) + (wg >> 3);
  const int bx = swz % nbx, by = swz / nbx;
  const int tid = threadIdx.x, lane = tid & 63, wid = tid >> 6;
  const int wr = wid >> 1, wc = wid & 1;
  const int lr = lane & 15, lg = lane >> 4;
  const int xs = lg ^ ((lr >> 1) & 3);
  const int aoffR = (wr * 64 + lr) * 64 + xs * 16;         // + m*1024 + buf
  const int boffR = 8192 + (wc * 128 + lr) * 64 + xs * 16; // + n*1024 + buf
  // staging: lane l covers row base+(l>>2), chunk (l&3)^((l>>3)&3)
  const int srow = lane >> 2;
  const int scolE = (((lane & 3) ^ ((lane >> 3) & 3)) << 3);
  const __hip_bfloat16* Ag = A + (size_t)(bx * 128 + wid * 32 + srow) * K + scolE;
  const __hip_bfloat16* Bg = Bt + (size_t)(by * 256 + wid * 64 + srow) * K + scolE;
  const size_t rK16 = (size_t)16 * K;
  char* dA = lds + wid * 2048;          // + buf*24576 (+j*1024, j=0..1)
  char* dB = lds + 8192 + wid * 4096;   // + buf*24576 (+j*1024, j=0..3)

#define STG(BUF, TS) {                                                   \
    gload16(Ag + (TS) * 32,        dA + (BUF) * 24576);                  \
    gload16(Ag + rK16 + (TS) * 32, dA + (BUF) * 24576 + 1024);           \
    gload16(Bg + (TS) * 32,            dB + (BUF) * 24576);              \
    gload16(Bg + rK16 + (TS) * 32,     dB + (BUF) * 24576 + 1024);       \
    gload16(Bg + 2 * rK16 + (TS) * 32, dB + (BUF) * 24576 + 2048);       \
    gload16(Bg + 3 * rK16 + (TS) * 32, dB + (BUF) * 24576 + 3072);       \
  }
#define BARRIER asm volatile("s_barrier" ::: "memory")
#define VW6 asm volatile("s_waitcnt vmcnt(6)" ::: "memory")
#define VW0 asm volatile("s_waitcnt vmcnt(0)" ::: "memory")

  f32x4 acc[4][8];
#pragma unroll
  for (int m = 0; m < 4; m++)
#pragma unroll
    for (int n = 0; n < 8; n++) acc[m][n] = f32x4{0.f, 0.f, 0.f, 0.f};
  bf16x8 rA[4], rB[8];

// one phase: read buf RB, optionally stage tile TS into buf SB, 32 MFMA.
#define PH(RB, SB, TS, DOSTG, ENDW) {                                    \
    _Pragma("unroll")                                                    \
    for (int m = 0; m < 4; m++)                                          \
      rA[m] = *(const bf16x8*)(lds + (RB) * 24576 + aoffR + m * 1024);   \
    _Pragma("unroll")                                                    \
    for (int n = 0; n < 8; n++)                                          \
      rB[n] = *(const bf16x8*)(lds + (RB) * 24576 + boffR + n * 1024);   \
    if (DOSTG) STG((SB), (TS));                                          \
    mm48(acc, rA, rB);                                                   \
    ENDW;                                                                \
    BARRIER;                                                             \
  }

  // prologue: stage tiles 0,1 into bufs 0,1 (12 gloads); tile0 landed at VW6
  STG(0, 0); STG(1, 1);
  VW6;
  BARRIER;

  for (int i = 0; i < 20; ++i) {
    const int t = 3 * i;
    PH(0, 2, t + 2, 1, VW6);    // tile 3i
    PH(1, 0, t + 3, 1, VW6);    // tile 3i+1
    PH(2, 1, t + 4, 1, VW6);    // tile 3i+2
  }
  PH(0, 2, 62, 1, VW6);         // t=60
  PH(1, 0, 63, 1, VW6);         // t=61
  PH(2, 0, 0, 0, VW0);          // t=62 (drain tile 63)
  PH(0, 0, 0, 0, (void)0);      // t=63
#undef PH
#undef STG
#undef BARRIER
#undef VW6
#undef VW0

  const int row0 = bx * 128 + wr * 64 + lg * 4;
  const int col0 = by * 256 + wc * 128 + lr;
#pragma unroll
  for (int m = 0; m < 4; m++)
#pragma unroll
    for (int n = 0; n < 8; n++) {
      size_t base = (size_t)(row0 + m * 16) * N + col0 + n * 16;
#pragma unroll
      for (int r = 0; r < 4; r++) {
        float v = acc[m][n][r];
        if constexpr (sizeof(OutT) == 2)
          Co[base + (size_t)r * N] = __float2bfloat16(v);
        else
          Co[base + (size_t)r * N] = v;
      }
    }
}

// ============ 128x256-tile 8-phase GEMM (ring-3), 8 waves — for proj =======
__device__ __forceinline__ void rdA4(bf16x8 (&d)[4], const char* p) {
#pragma unroll
  for (int m = 0; m < 4; m++) d[m] = *(const bf16x8*)(p + m * 1024);
}
__device__ __forceinline__ void rdB4(bf16x8 (&d)[4], const char* p) {
#pragma unroll
  for (int n = 0; n < 4; n++) d[n] = *(const bf16x8*)(p + n * 1024);
}
__device__ __forceinline__ void mm44(f32x4 (&acc)[4][4], const bf16x8 (&A_)[4],
                                     const bf16x8 (&B_)[4]) {
  __builtin_amdgcn_s_setprio(1);
#pragma unroll
  for (int m = 0; m < 4; m++)
#pragma unroll
    for (int n = 0; n < 4; n++)
      acc[m][n] = mfma16(A_[m], B_[n], acc[m][n]);
  __builtin_amdgcn_s_setprio(0);
}

template <typename OutT>
__global__ __launch_bounds__(512, 2) void k_gemm8b(const __hip_bfloat16* __restrict__ A,
    const __hip_bfloat16* __restrict__ Bt, OutT* __restrict__ Co,
    int M, int N) {
  constexpr int K = 2048;
  __shared__ __align__(16) char lds[147456];          // 3 x 48KB ring
  const int nbx = M >> 7;                              // 128-row tiles
  const int nwg = nbx * (N >> 8);                      // %8==0 for our shapes
  const int wg = blockIdx.x;
  const int swz = (wg & 7) * (nwg >> 3) + (wg >> 3);
  const int bx = swz % nbx, by = swz / nbx;
  const int tid = threadIdx.x, lane = tid & 63, wid = tid >> 6;
  const int wr = wid >> 2, wc = wid & 3;
  const int lr = lane & 15, lg = lane >> 4;
  const int roff = lr * 64 + (lg ^ ((lr >> 1) & 3)) * 16;
  const int srow = wid * 16 + (lane >> 2);             // [0,128)
  const int scol = (((lane & 3) ^ ((srow >> 1) & 3)) << 3);
  const __hip_bfloat16* Ag = A + (size_t)(bx * 128 + srow) * K + scol;
  const __hip_bfloat16* Bg = Bt + (size_t)(by * 256 + srow) * K + scol;
  char* ldsw = lds + wid * 1024;
  const size_t rstepB = (size_t)128 * K;
  const char* Ab = lds + wr * 4096 + roff;             // A: + kk*8192
  const char* Bb = lds + 16384 + wc * 4096 + roff;     // B: + kk*16384

#define STG_A(bufo, t, kk) gload16(Ag + (t) * 64 + (kk) * 32, \
                                   ldsw + (bufo) + (kk) * 8192)
#define STG_B(bufo, t, kk) { const __hip_bfloat16* g_ = Bg + (t) * 64 + (kk) * 32; \
    gload16(g_, ldsw + (bufo) + 16384 + (kk) * 16384);                              \
    gload16(g_ + rstepB, ldsw + (bufo) + 16384 + (kk) * 16384 + 8192); }
#define BARRIER asm volatile("s_barrier" ::: "memory")
#define VW6 asm volatile("s_waitcnt vmcnt(6)" ::: "memory")
#define VW0 asm volatile("s_waitcnt vmcnt(0)" ::: "memory")

  f32x4 acc[4][4];
#pragma unroll
  for (int m = 0; m < 4; m++)
#pragma unroll
    for (int n = 0; n < 4; n++) acc[m][n] = f32x4{0.f, 0.f, 0.f, 0.f};
  bf16x8 rA[4], rB[4];

#define TILE(RB, SB, TS, DOSTG, ENDW)                                   \
  {                                                                     \
    rdA4(rA, Ab + (RB));                                                \
    rdB4(rB, Bb + (RB));                                                \
    if (DOSTG) { STG_A((SB), (TS), 0); STG_B((SB), (TS), 0); }          \
    BARRIER;                                                            \
    mm44(acc, rA, rB);                                                  \
    BARRIER;                                                            \
    rdA4(rA, Ab + (RB) + 8192);                                         \
    rdB4(rB, Bb + (RB) + 16384);                                        \
    if (DOSTG) { STG_A((SB), (TS), 1); STG_B((SB), (TS), 1); }          \
    BARRIER;                                                            \
    mm44(acc, rA, rB);                                                  \
    ENDW;                                                               \
    BARRIER;                                                            \
  }

  // prologue: stage tiles 0,1 into bufs 0,1
  STG_A(0, 0, 0); STG_B(0, 0, 0); STG_A(0, 0, 1); STG_B(0, 0, 1);
  STG_A(49152, 1, 0); STG_B(49152, 1, 0); STG_A(49152, 1, 1); STG_B(49152, 1, 1);
  VW6;
  BARRIER;

  for (int i = 0; i < 10; ++i) {
    const int t = 3 * i;
    TILE(0,     98304, t + 2, 1, VW6);   // tile 3i   (buf0) stages -> buf2
    TILE(49152, 0,     t + 3, 1, VW6);   // tile 3i+1 (buf1) stages -> buf0
    TILE(98304, 49152, t + 4, 1, VW6);   // tile 3i+2 (buf2) stages -> buf1
  }
  TILE(0,     0, 0, 0, VW0);             // tile 30 (buf0), drain tile31
  TILE(49152, 0, 0, 0, (void)0);         // tile 31 (buf1)
#undef TILE
#undef STG_A
#undef STG_B
#undef BARRIER
#undef VW6
#undef VW0

  const int row0 = bx * 128 + wr * 64 + lg * 4;
  const int col0 = by * 256 + wc * 64 + lr;
#pragma unroll
  for (int m = 0; m < 4; m++)
#pragma unroll
    for (int n = 0; n < 4; n++) {
      size_t base = (size_t)(row0 + m * 16) * N + col0 + n * 16;
#pragma unroll
      for (int r = 0; r < 4; r++) {
        float v = acc[m][n][r];
        if constexpr (sizeof(OutT) == 2)
          Co[base + (size_t)r * N] = __float2bfloat16(v);
        else
          Co[base + (size_t)r * N] = v;
      }
    }
}

// ---------------- in-place QK RMSNorm over head dim (D=128) ----------------
__global__ __launch_bounds__(256) void k_qkrms(__hip_bfloat16* __restrict__ QKV,
    const float* __restrict__ qw, const float* __restrict__ kw) {
  int bt = blockIdx.x;
  int w = threadIdx.x >> 6, lane = threadIdx.x & 63;
  int hv = blockIdx.y * 4 + w;
  const float* wt; int col; float extra;
  if (hv < 16) { wt = qw; col = hv * Dc;             extra = QSCALE; }
  else         { wt = kw; col = Cc + (hv - 16) * Dc; extra = 1.0f;   }
  __hip_bfloat16* p = QKV + (size_t)bt * NQ + col + lane * 2;
  float x0 = __bfloat162float(p[0]);
  float x1 = __bfloat162float(p[1]);
  float ss = x0 * x0 + x1 * x1;
  for (int m = 1; m < 64; m <<= 1) ss += __shfl_xor(ss, m);
  float sc = rsqrtf(ss * (1.0f / Dc) + EPSc) * extra;
  p[0] = __float2bfloat16(x0 * sc * wt[lane * 2]);
  p[1] = __float2bfloat16(x1 * sc * wt[lane * 2 + 1]);
}

// ---------------- V transpose: (b,t,h,d) cols of QKV -> Vt (b,h,d,t) -------
__global__ __launch_bounds__(256) void k_vtrans(const __hip_bfloat16* __restrict__ QKV,
                                                __hip_bfloat16* __restrict__ Vt) {
  __shared__ __hip_bfloat16 tile[64][65];
  int bh = blockIdx.z, t0 = blockIdx.x * 64, d0 = blockIdx.y * 64;
  int b = bh >> 4, h = bh & 15;
  int c = threadIdx.x & 63, rb = threadIdx.x >> 6;
  for (int i = 0; i < 16; i++) {
    int r = rb * 16 + i;
    tile[r][c] = QKV[(size_t)(b * Tc + t0 + r) * NQ + 2 * Cc + h * Dc + d0 + c];
  }
  __syncthreads();
  for (int i = 0; i < 16; i++) {
    int r = rb * 16 + i;
    Vt[((size_t)bh * Dc + d0 + r) * Tc + t0 + c] = tile[c][r];
  }
}

// ---------------- flash attention: counted-vmcnt pipeline, r7 softmax ------
__global__ __launch_bounds__(256, 2) void k_attn(const __hip_bfloat16* __restrict__ QKV,
    const __hip_bfloat16* __restrict__ Vt, const float* __restrict__ subw,
    __hip_bfloat16* __restrict__ Y) {
  __shared__ __align__(16) __hip_bfloat16 Ks[2][64][128];   // 32 KB
  __shared__ __align__(16) __hip_bfloat16 Vs[2][128][64];   // 32 KB
  __shared__ __align__(16) __hip_bfloat16 Plds[4][16][72];  // 9 KB
  const int bh = blockIdx.x, pp = blockIdx.y;
  const int b = bh >> 4, h = bh & 15;
  const int w = threadIdx.x >> 6, lane = threadIdx.x & 63;
  const int lr = lane & 15, lg = lane >> 4;
  const float slope = exp2f(-0.5f * (float)(h + 1));
  const __hip_bfloat16* Kbase = QKV + (size_t)b * Tc * NQ + Cc + h * Dc;
  const __hip_bfloat16* Vbase = Vt + (size_t)bh * Dc * Tc;
  const int krow = (lane >> 4);
  const int kcolb = ((lane & 15) << 4);
  const int vrow = (lane >> 3);
  const int vcolb = ((lane & 7) << 4);
  f32x4 zero = {0.f, 0.f, 0.f, 0.f};

#define STAGE(bb, t)                                                              \
    {                                                                             \
      const int s0_ = (t) * 64;                                                   \
      for (int j = 0; j < 4; j++) {                                               \
        int row = w * 16 + j * 4 + krow;                                          \
        int cb = kcolb ^ ((row & 7) << 4);                                        \
        gload16(Kbase + (size_t)(s0_ + row) * NQ + (cb >> 1),                     \
                &Ks[bb][w * 16 + j * 4][0]);                                      \
      }                                                                           \
      for (int j = 0; j < 4; j++) {                                               \
        int row = w * 32 + j * 8 + vrow;                                          \
        int cb = vcolb ^ ((row & 7) << 4);                                        \
        gload16(Vbase + (size_t)row * Tc + s0_ + (cb >> 1),                       \
                &Vs[bb][w * 32 + j * 8][0]);                                      \
      }                                                                           \
    }
#define SBAR asm volatile("s_barrier" ::: "memory")
#define AVW8 asm volatile("s_waitcnt vmcnt(8)" ::: "memory")
#define AVW0 asm volatile("s_waitcnt vmcnt(0)" ::: "memory")
#define ALG0 asm volatile("s_waitcnt lgkmcnt(0)" ::: "memory")

  int buf = 0;
  for (int ti = 0; ti < 2; ti++) {
    const int qt = (ti == 0) ? (31 - pp) : pp;
    const int q0 = qt * 64 + w * 16;
    const int nchunk = qt + 1;
    bf16x8 aq[4];
    {
      const __hip_bfloat16* qb = QKV + (size_t)(b * Tc + q0 + lr) * NQ + h * Dc + lg * 8;
      for (int c = 0; c < 4; c++) aq[c] = *(const bf16x8*)(qb + c * 32);
    }
    f32x4 acc[8];
    for (int d = 0; d < 8; d++) acc[d] = zero;
    float mrow[4] = {-1e30f, -1e30f, -1e30f, -1e30f};
    float lrow[4] = {0.f, 0.f, 0.f, 0.f};

    SBAR;                    // protect K/V buffers vs previous q-tile readers
    STAGE(buf, 0);
    for (int t = 0; t < nchunk; t++) {
      if (t + 1 < nchunk) { STAGE(buf ^ 1, t + 1); AVW8; }
      else                { AVW0; }
      SBAR;
      const int s0 = t * 64;
      // ---- QK^T (16 MFMA) ----
      f32x4 s[4];
      for (int ss = 0; ss < 4; ss++) s[ss] = zero;
      __builtin_amdgcn_s_setprio(1);
      for (int c = 0; c < 4; c++)
        for (int ss = 0; ss < 4; ss++) {
          int kr = ss * 16 + lr;
          const bf16x8 kf = *(const bf16x8*)
              &Ks[buf][kr][((c * 64 + lg * 16) ^ ((kr & 7) << 4)) >> 1];
          s[ss] = mfma16(aq[c], kf, s[ss]);
        }
      __builtin_amdgcn_s_setprio(0);
      // ---- softmax (online) ----
      float ps[4][4], mt[4];
      for (int r = 0; r < 4; r++) mt[r] = -1e30f;
      for (int ss = 0; ss < 4; ss++) {
        int jj = s0 + ss * 16 + lr;
        for (int r = 0; r < 4; r++) {
          int i = q0 + lg * 4 + r;
          float pv = (jj <= i) ? s[ss][r] - slope * (float)(i - jj) : -1e30f;
          ps[ss][r] = pv;
          mt[r] = fmaxf(mt[r], pv);
        }
      }
      for (int m = 1; m < 16; m <<= 1)
        for (int r = 0; r < 4; r++) mt[r] = fmaxf(mt[r], __shfl_xor(mt[r], m));
      float corr[4], rs[4];
      for (int r = 0; r < 4; r++) {
        float mn = fmaxf(mrow[r], mt[r]);
        corr[r] = __expf(mrow[r] - mn);
        mrow[r] = mn;
        rs[r] = 0.f;
      }
      for (int ss = 0; ss < 4; ss++)
        for (int r = 0; r < 4; r++) {
          float e = __expf(ps[ss][r] - mrow[r]);
          ps[ss][r] = e;
          rs[r] += e;
        }
      for (int m = 1; m < 16; m <<= 1)
        for (int r = 0; r < 4; r++) rs[r] += __shfl_xor(rs[r], m);
      for (int r = 0; r < 4; r++) lrow[r] = lrow[r] * corr[r] + rs[r];
      for (int d = 0; d < 8; d++)
        for (int r = 0; r < 4; r++) acc[d][r] *= corr[r];
      // ---- P -> LDS, PV (16 MFMA) ----
      for (int ss = 0; ss < 4; ss++)
        for (int r = 0; r < 4; r++)
          Plds[w][lg * 4 + r][ss * 16 + lr] = __float2bfloat16(ps[ss][r]);
      bf16x8 pa0 = *(const bf16x8*)&Plds[w][lr][lg * 8];
      bf16x8 pa1 = *(const bf16x8*)&Plds[w][lr][32 + lg * 8];
      __builtin_amdgcn_s_setprio(1);
      for (int d = 0; d < 8; d++) {
        int vr = d * 16 + lr;
        const bf16x8 b0 = *(const bf16x8*)
            &Vs[buf][vr][((lg * 16) ^ ((vr & 7) << 4)) >> 1];
        const bf16x8 b1 = *(const bf16x8*)
            &Vs[buf][vr][((64 + lg * 16) ^ ((vr & 7) << 4)) >> 1];
        acc[d] = mfma16(pa0, b0, acc[d]);
        acc[d] = mfma16(pa1, b1, acc[d]);
      }
      __builtin_amdgcn_s_setprio(0);
      ALG0; SBAR;            // reads of buf done before next overwrite
      buf ^= 1;
    }
    // ---- epilogue: 1/l, subln rmsnorm, store ----
    float ssum[4] = {0.f, 0.f, 0.f, 0.f};
    for (int r = 0; r < 4; r++) {
      float rl = 1.0f / lrow[r];
      for (int d = 0; d < 8; d++) {
        float o = acc[d][r] * rl;
        acc[d][r] = o;
        ssum[r] += o * o;
      }
    }
    for (int m = 1; m < 16; m <<= 1)
      for (int r = 0; r < 4; r++) ssum[r] += __shfl_xor(ssum[r], m);
    float ms[4];
    for (int r = 0; r < 4; r++) ms[r] = rsqrtf(ssum[r] * (1.0f / Dc) + EPSc);
    for (int d = 0; d < 8; d++) {
      float wv = subw[d * 16 + lr];
      for (int r = 0; r < 4; r++) {
        float y = acc[d][r] * ms[r] * wv;
        Y[(size_t)(b * Tc + q0 + lg * 4 + r) * Cc + h * Dc + d * 16 + lr] =
            __float2bfloat16(y);
      }
    }
  }
#undef STAGE
#undef SBAR
#undef AVW8
#undef AVW0
#undef ALG0
}

extern "C" void kernel_launch(void* const* d_in, const int* in_sizes, int n_in,
                              void* d_out, int out_size, void* d_ws, size_t ws_size,
                              hipStream_t stream) {
  const float* x  = (const float*)d_in[0];
  const float* Wq = (const float*)d_in[1];
  const float* Wk = (const float*)d_in[2];
  const float* Wv = (const float*)d_in[3];
  const float* Wp = (const float*)d_in[4];
  const float* qw = (const float*)d_in[5];
  const float* kw = (const float*)d_in[6];
  const float* sw = (const float*)d_in[7];
  float* out = (float*)d_out;

  char* ws = (char*)d_ws;
  __hip_bfloat16* Xb    = (__hip_bfloat16*)(ws + 0);          // 16 MiB (4096x2048)
  __hip_bfloat16* Wqkv  = (__hip_bfloat16*)(ws + 16777216);   // 24 MiB (6144x2048, N-major)
  __hip_bfloat16* Wproj = (__hip_bfloat16*)(ws + 41943040);   //  8 MiB (2048x2048, N-major)
  __hip_bfloat16* QKV   = (__hip_bfloat16*)(ws + 50331648);   // 48 MiB (4096x6144)
  __hip_bfloat16* Vt    = (__hip_bfloat16*)(ws + 100663296);  // 16 MiB (b,h,d,t)
  __hip_bfloat16* Yb    = (__hip_bfloat16*)(ws + 117440512);  // 16 MiB (4096x2048)

  k_xconv<<<dim3((BTc * Cc) / 1024), 256, 0, stream>>>(x, Xb);
  k_wconv<<<dim3(32, 32, 4), 256, 0, stream>>>(Wq, Wk, Wv, Wp, Wqkv, Wproj);
  // QKV: 128x256 tiles, 4-wave 64x128 wave-tiles, 2 blocks/CU; 768 wgs
  k_gemm4<__hip_bfloat16><<<dim3((BTc / 128) * (NQ / 256)), 256, 0, stream>>>(
      Xb, Wqkv, QKV, BTc, NQ);
  k_qkrms<<<dim3(BTc, 8), 256, 0, stream>>>(QKV, qw, kw);
  k_vtrans<<<dim3(Tc / 64, Dc / 64, Bc * Hc), 256, 0, stream>>>(QKV, Vt);
  k_attn<<<dim3(Bc * Hc, 16), 256, 0, stream>>>(QKV, Vt, sw, Yb);
  // proj: 8-wave kernel, 256 wgs = 1/CU
  k_gemm8b<float><<<dim3((BTc / 128) * (Cc / 256)), 512, 0, stream>>>(
      Yb, Wproj, out, BTc, Cc);
}

// Round 12
// 261.981 us; speedup vs baseline: 1.1477x; 1.0679x over previous
//
#include <hip/hip_runtime.h>
#include <hip/hip_bf16.h>

// Problem constants
#define Bc 2
#define Tc 2048
#define Cc 2048
#define Hc 16
#define Dc 128
#define BTc 4096
#define NQ 6144            // 3*Cc
#define EPSc 1e-5f
#define QSCALE 0.08838834764831845f   // 1/sqrt(128)

typedef __attribute__((ext_vector_type(8))) short bf16x8;
typedef __attribute__((ext_vector_type(4))) short bf16x4;
typedef __attribute__((ext_vector_type(4))) float f32x4;

typedef struct { unsigned short u[4]; } us4;

__device__ __forceinline__ f32x4 mfma16(bf16x8 a, bf16x8 b, f32x4 c) {
  return __builtin_amdgcn_mfma_f32_16x16x32_bf16(a, b, c, 0, 0, 0);
}

__device__ __forceinline__ void gload16(const void* g, void* l) {
  __builtin_amdgcn_global_load_lds(
      (const __attribute__((address_space(1))) void*)g,
      (__attribute__((address_space(3))) void*)l, 16, 0, 0);
}

// ---------------- fp32 -> bf16 convert (x) ----------------
__global__ __launch_bounds__(256) void k_xconv(const float* __restrict__ x,
                                               __hip_bfloat16* __restrict__ xb) {
  size_t i = ((size_t)blockIdx.x * 256 + threadIdx.x) * 4;
  float4 v = *(const float4*)(x + i);
  union { __hip_bfloat16 h[4]; bf16x4 v4; } u;
  u.h[0] = __float2bfloat16(v.x); u.h[1] = __float2bfloat16(v.y);
  u.h[2] = __float2bfloat16(v.z); u.h[3] = __float2bfloat16(v.w);
  *(bf16x4*)(xb + i) = u.v4;
}

// ------- weight transpose+convert: W (K x N) fp32 -> Wt (N x K) bf16 -------
__global__ __launch_bounds__(256) void k_wconv(const float* __restrict__ Wq,
    const float* __restrict__ Wk, const float* __restrict__ Wv,
    const float* __restrict__ Wp, __hip_bfloat16* __restrict__ Wqkv_t,
    __hip_bfloat16* __restrict__ Wproj_t) {
  __shared__ float tile[64][65];
  int z = blockIdx.z;
  const float* src = (z == 0) ? Wq : (z == 1) ? Wk : (z == 2) ? Wv : Wp;
  __hip_bfloat16* dst = (z < 3) ? (Wqkv_t + (size_t)z * Cc * Cc) : Wproj_t;
  int k0 = blockIdx.x * 64, n0 = blockIdx.y * 64;
  int c = threadIdx.x & 63, rb = threadIdx.x >> 6;
  for (int i = 0; i < 16; i++) {
    int r = rb * 16 + i;
    tile[r][c] = src[(size_t)(k0 + r) * Cc + n0 + c];
  }
  __syncthreads();
  for (int i = 0; i < 16; i++) {
    int r = rb * 16 + i;
    dst[(size_t)(n0 + r) * Cc + k0 + c] = __float2bfloat16(tile[c][r]);
  }
}

// ============ 128x256-tile GEMM, 4 waves of 64x128, BK=32, ring-3 ==========
// MODE 0: plain (OutT out, row-major).  MODE 1 (QKV fused): region by>>3:
//   0 -> Q: rmsnorm(d=128 rows of acc, fp32) * qw * QSCALE -> QKV
//   1 -> K: rmsnorm * kw -> QKV
//   2 -> V: write transposed to Vt[(b*16+h)*128+d][t] (skip QKV)
// Wave's 128 cols = exactly one head (wc*128-aligned), so per-row sum over
// D=128 = 8 per-lane squares + shfl_xor{1,2,4,8} over the lr group.
__device__ __forceinline__ void mm48(f32x4 (&acc)[4][8], const bf16x8 (&A_)[4],
                                     const bf16x8 (&B_)[8]) {
  __builtin_amdgcn_s_setprio(1);
#pragma unroll
  for (int m = 0; m < 4; m++)
#pragma unroll
    for (int n = 0; n < 8; n++)
      acc[m][n] = mfma16(A_[m], B_[n], acc[m][n]);
  __builtin_amdgcn_s_setprio(0);
}

template <int MODE, typename OutT>
__global__ __launch_bounds__(256, 2) void k_gemm4(const __hip_bfloat16* __restrict__ A,
    const __hip_bfloat16* __restrict__ Bt, OutT* __restrict__ Co,
    int M, int N, const float* __restrict__ qw, const float* __restrict__ kw,
    __hip_bfloat16* __restrict__ Vt) {
  constexpr int K = 2048;
  __shared__ __align__(16) char lds[73728];            // 3 x 24KB ring
  const int nbx = M >> 7;                               // 128-row tiles
  const int nwg = nbx * (N >> 8);                       // %8==0
  const int wg = blockIdx.x;
  const int swz = (wg & 7) * (nwg >> 3) + (wg >> 3);
  const int bx = swz % nbx, by = swz / nbx;
  const int tid = threadIdx.x, lane = tid & 63, wid = tid >> 6;
  const int wr = wid >> 1, wc = wid & 1;
  const int lr = lane & 15, lg = lane >> 4;
  const int xs = lg ^ ((lr >> 1) & 3);
  const int aoffR = (wr * 64 + lr) * 64 + xs * 16;         // + m*1024 + buf
  const int boffR = 8192 + (wc * 128 + lr) * 64 + xs * 16; // + n*1024 + buf
  // staging: lane l covers row base+(l>>2), chunk (l&3)^((l>>3)&3)
  const int srow = lane >> 2;
  const int scolE = (((lane & 3) ^ ((lane >> 3) & 3)) << 3);
  const __hip_bfloat16* Ag = A + (size_t)(bx * 128 + wid * 32 + srow) * K + scolE;
  const __hip_bfloat16* Bg = Bt + (size_t)(by * 256 + wid * 64 + srow) * K + scolE;
  const size_t rK16 = (size_t)16 * K;
  char* dA = lds + wid * 2048;          // + buf*24576 (+j*1024)
  char* dB = lds + 8192 + wid * 4096;   // + buf*24576 (+j*1024)

#define STG(BUF, TS) {                                                   \
    gload16(Ag + (TS) * 32,        dA + (BUF) * 24576);                  \
    gload16(Ag + rK16 + (TS) * 32, dA + (BUF) * 24576 + 1024);           \
    gload16(Bg + (TS) * 32,            dB + (BUF) * 24576);              \
    gload16(Bg + rK16 + (TS) * 32,     dB + (BUF) * 24576 + 1024);       \
    gload16(Bg + 2 * rK16 + (TS) * 32, dB + (BUF) * 24576 + 2048);       \
    gload16(Bg + 3 * rK16 + (TS) * 32, dB + (BUF) * 24576 + 3072);       \
  }
#define BARRIER asm volatile("s_barrier" ::: "memory")
#define VW6 asm volatile("s_waitcnt vmcnt(6)" ::: "memory")
#define VW0 asm volatile("s_waitcnt vmcnt(0)" ::: "memory")

  f32x4 acc[4][8];
#pragma unroll
  for (int m = 0; m < 4; m++)
#pragma unroll
    for (int n = 0; n < 8; n++) acc[m][n] = f32x4{0.f, 0.f, 0.f, 0.f};
  bf16x8 rA[4], rB[8];

#define PH(RB, SB, TS, DOSTG, ENDW) {                                    \
    _Pragma("unroll")                                                    \
    for (int m = 0; m < 4; m++)                                          \
      rA[m] = *(const bf16x8*)(lds + (RB) * 24576 + aoffR + m * 1024);   \
    _Pragma("unroll")                                                    \
    for (int n = 0; n < 8; n++)                                          \
      rB[n] = *(const bf16x8*)(lds + (RB) * 24576 + boffR + n * 1024);   \
    if (DOSTG) STG((SB), (TS));                                          \
    mm48(acc, rA, rB);                                                   \
    ENDW;                                                                \
    BARRIER;                                                             \
  }

  // prologue: stage tiles 0,1 into bufs 0,1; tile0 landed at VW6
  STG(0, 0); STG(1, 1);
  VW6;
  BARRIER;

  for (int i = 0; i < 20; ++i) {
    const int t = 3 * i;
    PH(0, 2, t + 2, 1, VW6);    // tile 3i
    PH(1, 0, t + 3, 1, VW6);    // tile 3i+1
    PH(2, 1, t + 4, 1, VW6);    // tile 3i+2
  }
  PH(0, 2, 62, 1, VW6);         // t=60
  PH(1, 0, 63, 1, VW6);         // t=61
  PH(2, 0, 0, 0, VW0);          // t=62 (drain tile 63)
  PH(0, 0, 0, 0, (void)0);      // t=63
#undef PH
#undef STG
#undef BARRIER
#undef VW6
#undef VW0

  const int row0 = bx * 128 + wr * 64 + lg * 4;
  const int col0 = by * 256 + wc * 128 + lr;

  if (MODE == 1) {
    const int region = by >> 3;            // 0=Q, 1=K, 2=V
    if (region < 2) {
      const float* wsel = (region == 0) ? qw : kw;
      const float extra = (region == 0) ? QSCALE : 1.0f;
      float wv[8];
#pragma unroll
      for (int n = 0; n < 8; n++) wv[n] = wsel[n * 16 + lr];
#pragma unroll
      for (int m = 0; m < 4; m++) {
        float ss[4] = {0.f, 0.f, 0.f, 0.f};
#pragma unroll
        for (int n = 0; n < 8; n++)
#pragma unroll
          for (int r = 0; r < 4; r++) ss[r] += acc[m][n][r] * acc[m][n][r];
        for (int msk = 1; msk < 16; msk <<= 1)
#pragma unroll
          for (int r = 0; r < 4; r++) ss[r] += __shfl_xor(ss[r], msk);
        float sc[4];
#pragma unroll
        for (int r = 0; r < 4; r++)
          sc[r] = rsqrtf(ss[r] * (1.0f / Dc) + EPSc) * extra;
#pragma unroll
        for (int n = 0; n < 8; n++) {
          size_t base = (size_t)(row0 + m * 16) * N + col0 + n * 16;
#pragma unroll
          for (int r = 0; r < 4; r++)
            ((__hip_bfloat16*)Co)[base + (size_t)r * N] =
                __float2bfloat16(acc[m][n][r] * sc[r] * wv[n]);
        }
      }
    } else {
      // V: write transposed to Vt[(b*16+h)*128 + d][t]
      const int h = ((by - 16) * 256 + wc * 128) >> 7;   // 0..15
      const int bat = bx >> 4;                            // batch (rows/2048)
#pragma unroll
      for (int m = 0; m < 4; m++) {
        const int t0 = (row0 + m * 16) & (Tc - 1);
#pragma unroll
        for (int n = 0; n < 8; n++) {
          union { us4 p; unsigned long long q; } u;
#pragma unroll
          for (int r = 0; r < 4; r++) {
            union { __hip_bfloat16 h16; unsigned short s; } cv;
            cv.h16 = __float2bfloat16(acc[m][n][r]);
            u.p.u[r] = cv.s;
          }
          __hip_bfloat16* dst = Vt +
              ((size_t)(bat * 16 + h) * 128 + n * 16 + lr) * Tc + t0;
          *(unsigned long long*)dst = u.q;
        }
      }
    }
  } else {
#pragma unroll
    for (int m = 0; m < 4; m++)
#pragma unroll
      for (int n = 0; n < 8; n++) {
        size_t base = (size_t)(row0 + m * 16) * N + col0 + n * 16;
#pragma unroll
        for (int r = 0; r < 4; r++) {
          float v = acc[m][n][r];
          if constexpr (sizeof(OutT) == 2)
            Co[base + (size_t)r * N] = __float2bfloat16(v);
          else
            Co[base + (size_t)r * N] = v;
        }
      }
  }
}

// ---------------- flash attention: counted-vmcnt pipeline, r7 softmax ------
__global__ __launch_bounds__(256, 2) void k_attn(const __hip_bfloat16* __restrict__ QKV,
    const __hip_bfloat16* __restrict__ Vt, const float* __restrict__ subw,
    __hip_bfloat16* __restrict__ Y) {
  __shared__ __align__(16) __hip_bfloat16 Ks[2][64][128];   // 32 KB
  __shared__ __align__(16) __hip_bfloat16 Vs[2][128][64];   // 32 KB
  __shared__ __align__(16) __hip_bfloat16 Plds[4][16][72];  // 9 KB
  const int bh = blockIdx.x, pp = blockIdx.y;
  const int b = bh >> 4, h = bh & 15;
  const int w = threadIdx.x >> 6, lane = threadIdx.x & 63;
  const int lr = lane & 15, lg = lane >> 4;
  const float slope = exp2f(-0.5f * (float)(h + 1));
  const __hip_bfloat16* Kbase = QKV + (size_t)b * Tc * NQ + Cc + h * Dc;
  const __hip_bfloat16* Vbase = Vt + (size_t)bh * Dc * Tc;
  const int krow = (lane >> 4);
  const int kcolb = ((lane & 15) << 4);
  const int vrow = (lane >> 3);
  const int vcolb = ((lane & 7) << 4);
  f32x4 zero = {0.f, 0.f, 0.f, 0.f};

#define STAGE(bb, t)                                                              \
    {                                                                             \
      const int s0_ = (t) * 64;                                                   \
      for (int j = 0; j < 4; j++) {                                               \
        int row = w * 16 + j * 4 + krow;                                          \
        int cb = kcolb ^ ((row & 7) << 4);                                        \
        gload16(Kbase + (size_t)(s0_ + row) * NQ + (cb >> 1),                     \
                &Ks[bb][w * 16 + j * 4][0]);                                      \
      }                                                                           \
      for (int j = 0; j < 4; j++) {                                               \
        int row = w * 32 + j * 8 + vrow;                                          \
        int cb = vcolb ^ ((row & 7) << 4);                                        \
        gload16(Vbase + (size_t)row * Tc + s0_ + (cb >> 1),                       \
                &Vs[bb][w * 32 + j * 8][0]);                                      \
      }                                                                           \
    }
#define SBAR asm volatile("s_barrier" ::: "memory")
#define AVW8 asm volatile("s_waitcnt vmcnt(8)" ::: "memory")
#define AVW0 asm volatile("s_waitcnt vmcnt(0)" ::: "memory")
#define ALG0 asm volatile("s_waitcnt lgkmcnt(0)" ::: "memory")

  int buf = 0;
  for (int ti = 0; ti < 2; ti++) {
    const int qt = (ti == 0) ? (31 - pp) : pp;
    const int q0 = qt * 64 + w * 16;
    const int nchunk = qt + 1;
    bf16x8 aq[4];
    {
      const __hip_bfloat16* qb = QKV + (size_t)(b * Tc + q0 + lr) * NQ + h * Dc + lg * 8;
      for (int c = 0; c < 4; c++) aq[c] = *(const bf16x8*)(qb + c * 32);
    }
    f32x4 acc[8];
    for (int d = 0; d < 8; d++) acc[d] = zero;
    float mrow[4] = {-1e30f, -1e30f, -1e30f, -1e30f};
    float lrow[4] = {0.f, 0.f, 0.f, 0.f};

    SBAR;                    // protect K/V buffers vs previous q-tile readers
    STAGE(buf, 0);
    for (int t = 0; t < nchunk; t++) {
      if (t + 1 < nchunk) { STAGE(buf ^ 1, t + 1); AVW8; }
      else                { AVW0; }
      SBAR;
      const int s0 = t * 64;
      // ---- QK^T (16 MFMA) ----
      f32x4 s[4];
      for (int ss = 0; ss < 4; ss++) s[ss] = zero;
      __builtin_amdgcn_s_setprio(1);
      for (int c = 0; c < 4; c++)
        for (int ss = 0; ss < 4; ss++) {
          int kr = ss * 16 + lr;
          const bf16x8 kf = *(const bf16x8*)
              &Ks[buf][kr][((c * 64 + lg * 16) ^ ((kr & 7) << 4)) >> 1];
          s[ss] = mfma16(aq[c], kf, s[ss]);
        }
      __builtin_amdgcn_s_setprio(0);
      // ---- softmax (online) ----
      float ps[4][4], mt[4];
      for (int r = 0; r < 4; r++) mt[r] = -1e30f;
      for (int ss = 0; ss < 4; ss++) {
        int jj = s0 + ss * 16 + lr;
        for (int r = 0; r < 4; r++) {
          int i = q0 + lg * 4 + r;
          float pv = (jj <= i) ? s[ss][r] - slope * (float)(i - jj) : -1e30f;
          ps[ss][r] = pv;
          mt[r] = fmaxf(mt[r], pv);
        }
      }
      for (int m = 1; m < 16; m <<= 1)
        for (int r = 0; r < 4; r++) mt[r] = fmaxf(mt[r], __shfl_xor(mt[r], m));
      float corr[4], rs[4];
      for (int r = 0; r < 4; r++) {
        float mn = fmaxf(mrow[r], mt[r]);
        corr[r] = __expf(mrow[r] - mn);
        mrow[r] = mn;
        rs[r] = 0.f;
      }
      for (int ss = 0; ss < 4; ss++)
        for (int r = 0; r < 4; r++) {
          float e = __expf(ps[ss][r] - mrow[r]);
          ps[ss][r] = e;
          rs[r] += e;
        }
      for (int m = 1; m < 16; m <<= 1)
        for (int r = 0; r < 4; r++) rs[r] += __shfl_xor(rs[r], m);
      for (int r = 0; r < 4; r++) lrow[r] = lrow[r] * corr[r] + rs[r];
      for (int d = 0; d < 8; d++)
        for (int r = 0; r < 4; r++) acc[d][r] *= corr[r];
      // ---- P -> LDS, PV (16 MFMA) ----
      for (int ss = 0; ss < 4; ss++)
        for (int r = 0; r < 4; r++)
          Plds[w][lg * 4 + r][ss * 16 + lr] = __float2bfloat16(ps[ss][r]);
      bf16x8 pa0 = *(const bf16x8*)&Plds[w][lr][lg * 8];
      bf16x8 pa1 = *(const bf16x8*)&Plds[w][lr][32 + lg * 8];
      __builtin_amdgcn_s_setprio(1);
      for (int d = 0; d < 8; d++) {
        int vr = d * 16 + lr;
        const bf16x8 b0 = *(const bf16x8*)
            &Vs[buf][vr][((lg * 16) ^ ((vr & 7) << 4)) >> 1];
        const bf16x8 b1 = *(const bf16x8*)
            &Vs[buf][vr][((64 + lg * 16) ^ ((vr & 7) << 4)) >> 1];
        acc[d] = mfma16(pa0, b0, acc[d]);
        acc[d] = mfma16(pa1, b1, acc[d]);
      }
      __builtin_amdgcn_s_setprio(0);
      ALG0; SBAR;            // reads of buf done before next overwrite
      buf ^= 1;
    }
    // ---- epilogue: 1/l, subln rmsnorm, store ----
    float ssum[4] = {0.f, 0.f, 0.f, 0.f};
    for (int r = 0; r < 4; r++) {
      float rl = 1.0f / lrow[r];
      for (int d = 0; d < 8; d++) {
        float o = acc[d][r] * rl;
        acc[d][r] = o;
        ssum[r] += o * o;
      }
    }
    for (int m = 1; m < 16; m <<= 1)
      for (int r = 0; r < 4; r++) ssum[r] += __shfl_xor(ssum[r], m);
    float ms[4];
    for (int r = 0; r < 4; r++) ms[r] = rsqrtf(ssum[r] * (1.0f / Dc) + EPSc);
    for (int d = 0; d < 8; d++) {
      float wv = subw[d * 16 + lr];
      for (int r = 0; r < 4; r++) {
        float y = acc[d][r] * ms[r] * wv;
        Y[(size_t)(b * Tc + q0 + lg * 4 + r) * Cc + h * Dc + d * 16 + lr] =
            __float2bfloat16(y);
      }
    }
  }
#undef STAGE
#undef SBAR
#undef AVW8
#undef AVW0
#undef ALG0
}

extern "C" void kernel_launch(void* const* d_in, const int* in_sizes, int n_in,
                              void* d_out, int out_size, void* d_ws, size_t ws_size,
                              hipStream_t stream) {
  const float* x  = (const float*)d_in[0];
  const float* Wq = (const float*)d_in[1];
  const float* Wk = (const float*)d_in[2];
  const float* Wv = (const float*)d_in[3];
  const float* Wp = (const float*)d_in[4];
  const float* qw = (const float*)d_in[5];
  const float* kw = (const float*)d_in[6];
  const float* sw = (const float*)d_in[7];
  float* out = (float*)d_out;

  char* ws = (char*)d_ws;
  __hip_bfloat16* Xb    = (__hip_bfloat16*)(ws + 0);          // 16 MiB (4096x2048)
  __hip_bfloat16* Wqkv  = (__hip_bfloat16*)(ws + 16777216);   // 24 MiB (6144x2048, N-major)
  __hip_bfloat16* Wproj = (__hip_bfloat16*)(ws + 41943040);   //  8 MiB (2048x2048, N-major)
  __hip_bfloat16* QKV   = (__hip_bfloat16*)(ws + 50331648);   // 48 MiB (4096x6144)
  __hip_bfloat16* Vt    = (__hip_bfloat16*)(ws + 100663296);  // 16 MiB (b,h,d,t)
  __hip_bfloat16* Yb    = (__hip_bfloat16*)(ws + 117440512);  // 16 MiB (4096x2048)

  k_xconv<<<dim3((BTc * Cc) / 1024), 256, 0, stream>>>(x, Xb);
  k_wconv<<<dim3(32, 32, 4), 256, 0, stream>>>(Wq, Wk, Wv, Wp, Wqkv, Wproj);
  // QKV GEMM with fused QK-RMSNorm (+QSCALE) and V-transpose; 768 wgs
  k_gemm4<1, __hip_bfloat16><<<dim3((BTc / 128) * (NQ / 256)), 256, 0, stream>>>(
      Xb, Wqkv, QKV, BTc, NQ, qw, kw, Vt);
  k_attn<<<dim3(Bc * Hc, 16), 256, 0, stream>>>(QKV, Vt, sw, Yb);
  // proj: plain mode, 256 wgs
  k_gemm4<0, float><<<dim3((BTc / 128) * (Cc / 256)), 256, 0, stream>>>(
      Yb, Wproj, out, BTc, Cc, nullptr, nullptr, nullptr);
}